// Round 17
// baseline (117.781 us; speedup 1.0000x reference)
//
#include <hip/hip_runtime.h>
#include <cmath>

#define B_ 2
#define S_ 2048
#define E_ 1024
#define H_ 16
#define D_ 64

typedef __attribute__((ext_vector_type(8)))  short  bf16x8;
typedef __attribute__((ext_vector_type(4)))  float  f32x4;
typedef __attribute__((ext_vector_type(16))) float  f32x16;
typedef __attribute__((ext_vector_type(8)))  unsigned short ushort8;
typedef __attribute__((ext_vector_type(4)))  unsigned short ushort4v;
typedef __attribute__((ext_vector_type(4)))  unsigned int   u32x4;
typedef unsigned int u32;

__device__ __forceinline__ ushort f2bf(float f) {
    u32 u = __float_as_uint(f);
    u32 r = (u + 0x7fffu + ((u >> 16) & 1u)) >> 16;
    return (ushort)r;
}
__device__ __forceinline__ void gload_lds16(const ushort* gp, ushort* lp) {
    auto g = (const __attribute__((address_space(1))) u32*)gp;
    auto l = (__attribute__((address_space(3))) u32*)lp;
    __builtin_amdgcn_global_load_lds(g, l, 16, 0, 0);
}
__device__ __forceinline__ u32 cvtpk_bf16(float lo, float hi) {
    u32 r;
    asm("v_cvt_pk_bf16_f32 %0, %1, %2" : "=v"(r) : "v"(lo), "v"(hi));
    return r;
}
// raw v_exp_f32 (2^x); input always <= 0 here, hw handles -inf -> 0
__device__ __forceinline__ float hw_exp2(float x) {
    float r;
    asm("v_exp_f32 %0, %1" : "=v"(r) : "v"(x));
    return r;
}
// hardware sin/cos of (2*pi*rev); v_fract first keeps input in-domain
__device__ __forceinline__ void hw_sincos_rev(float rev, float* sn, float* cs) {
    float fr;
    asm("v_fract_f32 %0, %1" : "=v"(fr) : "v"(rev));
    asm("v_sin_f32 %0, %1" : "=v"(*sn) : "v"(fr));
    asm("v_cos_f32 %0, %1" : "=v"(*cs) : "v"(fr));
}

// ---------------------------------------------------------------------------
// cast x (f32 -> bf16), 8 elems/thread
// ---------------------------------------------------------------------------
__global__ __launch_bounds__(256) void cast_x(const float* __restrict__ in,
                                              ushort* __restrict__ out) {
    const int idx = blockIdx.x * 256 + threadIdx.x;
    const float4 a = *reinterpret_cast<const float4*>(&in[(size_t)idx * 8]);
    const float4 b = *reinterpret_cast<const float4*>(&in[(size_t)idx * 8 + 4]);
    ushort8 o;
    o[0] = f2bf(a.x); o[1] = f2bf(a.y); o[2] = f2bf(a.z); o[3] = f2bf(a.w);
    o[4] = f2bf(b.x); o[5] = f2bf(b.y); o[6] = f2bf(b.z); o[7] = f2bf(b.w);
    *reinterpret_cast<ushort8*>(&out[(size_t)idx * 8]) = o;
}

// ---------------------------------------------------------------------------
// cast + transpose weights: W[k][n] f32 -> Wt[n][k] bf16  (1024x1024 each).
// 64-k tiles + packed u32 stores (2 bf16 per store, coalesced).
// ---------------------------------------------------------------------------
__global__ __launch_bounds__(256) void castT_w(
    const float* __restrict__ Wq, const float* __restrict__ Wk,
    const float* __restrict__ Wv, const float* __restrict__ Wo,
    ushort* __restrict__ WtQKV, ushort* __restrict__ WtO)
{
    __shared__ float tile[64][33];
    const float* src; ushort* dst;
    switch (blockIdx.z) {
        case 0:  src = Wq; dst = WtQKV;                 break;
        case 1:  src = Wk; dst = WtQKV + 1024 * 1024;   break;
        case 2:  src = Wv; dst = WtQKV + 2048 * 1024;   break;
        default: src = Wo; dst = WtO;                   break;
    }
    const int k0 = blockIdx.y * 64, n0 = blockIdx.x * 32;
    const int tn = threadIdx.x & 31, tk = threadIdx.x >> 5;   // 0..31, 0..7
    #pragma unroll
    for (int p = 0; p < 8; ++p)
        tile[p * 8 + tk][tn] = src[(size_t)(k0 + p * 8 + tk) * 1024 + n0 + tn];
    __syncthreads();
    const int kp = (threadIdx.x & 31) * 2, nq = threadIdx.x >> 5;
    #pragma unroll
    for (int q = 0; q < 4; ++q) {
        const int n = q * 8 + nq;
        const u32 v = (u32)f2bf(tile[kp][n]) | ((u32)f2bf(tile[kp + 1][n]) << 16);
        *reinterpret_cast<u32*>(&dst[(size_t)(n0 + n) * 1024 + k0 + kp]) = v;
    }
}

// ---------------------------------------------------------------------------
// QKV GEMM (M=4096, N=3072, K=1024), 128x128 tile, BK=64, T2-swizzled LDS.
// r17: double-buffered LDS + counted vmcnt(8) + raw s_barrier (the r12
// pattern proven on gemm_out) -> next K-step's 8 global_load_lds stay in
// flight across the barrier.  64 KB LDS -> 2 blocks/CU (launch_bounds 2).
// Epilogue fuses bias + RoPE (HW v_sin/v_cos); Q scaled by 0.125*log2(e).
// Writes Q->Qb, K->Kb (row-major), V->Vt (transposed).
// ---------------------------------------------------------------------------
__global__ __launch_bounds__(256, 2) void gemm_qkv(
    const ushort* __restrict__ A, const ushort* __restrict__ Bt,
    const float* __restrict__ bq, const float* __restrict__ bk,
    const float* __restrict__ bv,
    ushort* __restrict__ Qb, ushort* __restrict__ Kb, ushort* __restrict__ Vt)
{
    __shared__ ushort As[2][128 * 64];
    __shared__ ushort Bs[2][128 * 64];
    const int t = threadIdx.x, w = t >> 6, l = t & 63;
    const int lr = l & 15, lg = l >> 4;
    const int wr = w >> 1, wc = w & 1;
    const int row0 = blockIdx.y * 128, col0 = blockIdx.x * 128;

    f32x4 acc[4][4] = {};

    auto STAGE = [&](int buf, int k0) {
        #pragma unroll
        for (int i = 0; i < 4; ++i) {
            const int r  = w * 32 + i * 8 + (l >> 3);
            const int cs = ((l & 7) ^ (r & 7)) * 8;          // src pre-swizzle
            gload_lds16(&A [(size_t)(row0 + r) * 1024 + k0 + cs], &As[buf][(w * 32 + i * 8) * 64]);
            gload_lds16(&Bt[(size_t)(col0 + r) * 1024 + k0 + cs], &Bs[buf][(w * 32 + i * 8) * 64]);
        }
    };

    STAGE(0, 0);
    int cur = 0;

    for (int k0 = 0; k0 < 1024; k0 += 64) {
        if (k0 + 64 < 1024) {
            STAGE(cur ^ 1, k0 + 64);
            asm volatile("s_waitcnt vmcnt(8)" ::: "memory");  // current tile only
        } else {
            asm volatile("s_waitcnt vmcnt(0)" ::: "memory");
        }
        __builtin_amdgcn_s_barrier();

        #pragma unroll
        for (int kk = 0; kk < 2; ++kk) {
            bf16x8 af[4], bfr[4];
            #pragma unroll
            for (int m = 0; m < 4; ++m)
                af[m] = *reinterpret_cast<const bf16x8*>(
                    &As[cur][(wr * 64 + m * 16 + lr) * 64 + (((kk * 4 + lg) ^ (lr & 7)) * 8)]);
            #pragma unroll
            for (int n = 0; n < 4; ++n)
                bfr[n] = *reinterpret_cast<const bf16x8*>(
                    &Bs[cur][(wc * 64 + n * 16 + lr) * 64 + (((kk * 4 + lg) ^ (lr & 7)) * 8)]);
            #pragma unroll
            for (int m = 0; m < 4; ++m)
                #pragma unroll
                for (int n = 0; n < 4; ++n)
                    acc[m][n] = __builtin_amdgcn_mfma_f32_16x16x32_bf16(
                        af[m], bfr[n], acc[m][n], 0, 0, 0);
        }
        __builtin_amdgcn_s_barrier();          // reads of cur done before reuse
        cur ^= 1;
    }

    const int cbase = col0 + wc * 64;          // wave's 64-col span (one head)
    const int cls   = cbase >> 10;             // 0=Q, 1=K, 2=V
    const int hcol  = cbase & 1023;            // head-aligned col within 1024
    const float* bias = (cls == 0) ? bq : (cls == 1 ? bk : bv);

    if (cls < 2) {
        ushort* dst = (cls == 0) ? Qb : Kb;
        const float qscale = (cls == 0) ? 0.1803368801f : 1.0f;  // 0.125*log2(e)
        #pragma unroll
        for (int m = 0; m < 4; ++m) {
            const int rbase = row0 + wr * 64 + m * 16 + lg * 4;
            #pragma unroll
            for (int n = 0; n < 2; ++n) {
                const int i    = n * 16 + lr;                  // 0..31
                const float b0 = bias[hcol + i];
                const float b1 = bias[hcol + i + 32];
                // invf / (2*pi): angle in revolutions = s * invf_rev
                const float invf_rev =
                    exp2f(-(float)i * 0.415241012f) * 0.15915494309f;
                #pragma unroll
                for (int r = 0; r < 4; ++r) {
                    const int row = rbase + r;
                    const int s   = row & (S_ - 1);
                    float sn, cs_;
                    hw_sincos_rev((float)s * invf_rev, &sn, &cs_);
                    const float v0 = acc[m][n][r]     + b0;
                    const float v1 = acc[m][n + 2][r] + b1;
                    dst[(size_t)row * 1024 + hcol + i]      = f2bf((v0 * cs_ - v1 * sn) * qscale);
                    dst[(size_t)row * 1024 + hcol + i + 32] = f2bf((v1 * cs_ + v0 * sn) * qscale);
                }
            }
        }
    } else {
        const int h = hcol >> 6;
        #pragma unroll
        for (int m = 0; m < 4; ++m) {
            const int rbase = row0 + wr * 64 + m * 16 + lg * 4;
            const int bb = rbase >> 11, s0 = rbase & (S_ - 1);
            #pragma unroll
            for (int n = 0; n < 4; ++n) {
                const int d = n * 16 + lr;
                const float bia = bias[hcol + d];
                ushort4v pk;
                #pragma unroll
                for (int r = 0; r < 4; ++r) pk[r] = f2bf(acc[m][n][r] + bia);
                *reinterpret_cast<ushort4v*>(
                    &Vt[((size_t)(bb * 16 + h) * 64 + d) * S_ + s0]) = pk;
            }
        }
    }
}

// ---------------------------------------------------------------------------
// Output GEMM: C[M,1024] f32 = A @ Wt^T + bias.  Dbuf + counted vmcnt(8) +
// raw s_barrier (verified win r12).
// ---------------------------------------------------------------------------
__global__ __launch_bounds__(256, 1) void gemm_out(
    const ushort* __restrict__ A, const ushort* __restrict__ Bt,
    const float* __restrict__ bias, float* __restrict__ C, int N, int K)
{
    __shared__ ushort As[2][128 * 64];
    __shared__ ushort Bs[2][128 * 64];
    const int t = threadIdx.x, w = t >> 6, l = t & 63;
    const int lr = l & 15, lg = l >> 4;
    const int wr = w >> 1, wc = w & 1;
    const int row0 = blockIdx.y * 128, col0 = blockIdx.x * 128;

    f32x4 acc[4][4] = {};

    auto STAGE = [&](int buf, int k0) {
        #pragma unroll
        for (int i = 0; i < 4; ++i) {
            const int r  = w * 32 + i * 8 + (l >> 3);
            const int cs = ((l & 7) ^ (r & 7)) * 8;
            gload_lds16(&A [(size_t)(row0 + r) * K + k0 + cs], &As[buf][(w * 32 + i * 8) * 64]);
            gload_lds16(&Bt[(size_t)(col0 + r) * K + k0 + cs], &Bs[buf][(w * 32 + i * 8) * 64]);
        }
    };

    STAGE(0, 0);
    int cur = 0;

    for (int k0 = 0; k0 < K; k0 += 64) {
        if (k0 + 64 < K) {
            STAGE(cur ^ 1, k0 + 64);
            asm volatile("s_waitcnt vmcnt(8)" ::: "memory");
        } else {
            asm volatile("s_waitcnt vmcnt(0)" ::: "memory");
        }
        __builtin_amdgcn_s_barrier();

        #pragma unroll
        for (int kk = 0; kk < 2; ++kk) {
            bf16x8 af[4], bfr[4];
            #pragma unroll
            for (int m = 0; m < 4; ++m)
                af[m] = *reinterpret_cast<const bf16x8*>(
                    &As[cur][(wr * 64 + m * 16 + lr) * 64 + (((kk * 4 + lg) ^ (lr & 7)) * 8)]);
            #pragma unroll
            for (int n = 0; n < 4; ++n)
                bfr[n] = *reinterpret_cast<const bf16x8*>(
                    &Bs[cur][(wc * 64 + n * 16 + lr) * 64 + (((kk * 4 + lg) ^ (lr & 7)) * 8)]);
            #pragma unroll
            for (int m = 0; m < 4; ++m)
                #pragma unroll
                for (int n = 0; n < 4; ++n)
                    acc[m][n] = __builtin_amdgcn_mfma_f32_16x16x32_bf16(
                        af[m], bfr[n], acc[m][n], 0, 0, 0);
        }
        __builtin_amdgcn_s_barrier();
        cur ^= 1;
    }

    #pragma unroll
    for (int m = 0; m < 4; ++m) {
        const int rbase = row0 + wr * 64 + m * 16 + lg * 4;
        #pragma unroll
        for (int n = 0; n < 4; ++n) {
            const int c = col0 + wc * 64 + n * 16 + lr;
            const float bv = bias[c];
            #pragma unroll
            for (int r = 0; r < 4; ++r)
                C[(size_t)(rbase + r) * N + c] = acc[m][n][r] + bv;
        }
    }
}

// ---------------------------------------------------------------------------
// attn13 (kept from r16): KVBLK=128, balanced CU pairs, split online softmax
// (2 sequential 64-key flash updates per tile), in-register machinery.
// ---------------------------------------------------------------------------
__global__ __launch_bounds__(256, 2) void attn13(
    const ushort* __restrict__ Qb, const ushort* __restrict__ Kb,
    const ushort* __restrict__ Vt, ushort* __restrict__ AO)
{
    __shared__ ushort Ks[2][128 * 64];
    __shared__ ushort Vs[2][64 * 128];

    const int t = threadIdx.x, w = t >> 6, l = t & 63;
    const int lq = l & 31, hi = l >> 5;
    const int idx = blockIdx.x;
    const int bh = idx & 31, b = bh >> 4, h = bh & 15;
    const int g8 = idx >> 5;                   // 0..15
    const int qb = (idx < 256) ? (15 - g8) : (g8 - 8);   // balanced CU pairs
    const int q0 = qb * 128, qw = q0 + w * 32;
    const int qg = qw + lq;                    // this lane's q row

    const ushort* Kbh = Kb + (size_t)b * S_ * 1024 + h * 64;
    const ushort* Vbh = Vt + (size_t)bh * 64 * S_;

    // Q fragments (B-operand): qf[dc] = Q[qg][16*dc + 8*hi + j]
    bf16x8 qf[4];
    {
        const ushort* qrow = Qb + (size_t)(b * S_ + qg) * 1024 + h * 64 + 8 * hi;
        #pragma unroll
        for (int dc = 0; dc < 4; ++dc)
            qf[dc] = *reinterpret_cast<const bf16x8*>(qrow + 16 * dc);
    }

    f32x16 oacc[2] = {};                       // O^T: rows=d, col=q(lane)
    float mrow = -3.0e38f, lrow = 0.f;

    auto STAGE = [&](int buf, int kt) {
        // K: 128 keys x 64 d, 16 KB -> 4 instrs.  Linear dest, pre-swizzled src.
        #pragma unroll
        for (int i = 0; i < 4; ++i) {
            const int cid = i * 256 + t;                     // 0..1023
            const int r   = cid >> 3;                        // key 0..127
            const int cs  = ((cid & 7) ^ (r & 7)) * 8;
            const int db  = (i * 256 + w * 64) * 8;          // wave-uniform dest
            gload_lds16(&Kbh[(size_t)(kt + r) * 1024 + cs], &Ks[buf][db]);
        }
        // V: 64 d x 128 keys, 16 KB -> 4 instrs.  16-chunk XOR swizzle.
        #pragma unroll
        for (int i = 0; i < 4; ++i) {
            const int cid = i * 256 + t;
            const int d   = cid >> 4;                        // 0..63
            const int cs  = ((cid & 15) ^ (d & 15)) * 8;
            const int db  = (i * 256 + w * 64) * 8;
            gload_lds16(&Vbh[(size_t)d * S_ + kt + cs], &Vs[buf][db]);
        }
    };

    const int kend = q0 + 128;
    STAGE(0, 0);
    int cur = 0;

    for (int kt = 0; kt < kend; kt += 128) {
        if (kt + 128 < kend) {
            STAGE(cur ^ 1, kt + 128);
            asm volatile("s_waitcnt vmcnt(8)" ::: "memory");  // current tile only
        } else {
            asm volatile("s_waitcnt vmcnt(0)" ::: "memory");
        }
        __builtin_amdgcn_s_barrier();

        {
            const ushort* Kc = &Ks[cur][0];
            const ushort* Vc = &Vs[cur][0];

            // ---- S^T = K @ Q^T over 128 keys: all 4 subs ISSUED up front ----
            f32x16 sacc[4] = {};
            __builtin_amdgcn_s_setprio(1);
            #pragma unroll
            for (int sub = 0; sub < 4; ++sub) {
                const int rK = sub * 32 + lq;
                const int rx = lq & 7;
                #pragma unroll
                for (int dc = 0; dc < 4; ++dc) {
                    const bf16x8 kf = *reinterpret_cast<const bf16x8*>(
                        &Kc[rK * 64 + (((2 * dc + hi) ^ rx) * 8)]);
                    sacc[sub] = __builtin_amdgcn_mfma_f32_32x32x16_bf16(
                        kf, qf[dc], sacc[sub], 0, 0, 0);
                }
            }
            __builtin_amdgcn_s_setprio(0);

            // ---- two sequential 64-key online-softmax updates ----
            #pragma unroll
            for (int hf = 0; hf < 2; ++hf) {
                const int sA = 2 * hf, sB = 2 * hf + 1;

                // causal mask (boundary subs only; full-masked subs -> p=0)
                #pragma unroll
                for (int sub = sA; sub <= sB; ++sub)
                    if (kt + sub * 32 + 31 > qw) {
                        #pragma unroll
                        for (int r = 0; r < 16; ++r) {
                            const int kg = kt + sub * 32 + (r & 3) + 8 * (r >> 2) + 4 * hi;
                            if (kg > qg) sacc[sub][r] = -1.0e30f;
                        }
                    }

                // row max over this half's 64 scores: tree + cross-half swap
                float mx[16];
                #pragma unroll
                for (int r = 0; r < 16; ++r)
                    mx[r] = fmaxf(sacc[sA][r], sacc[sB][r]);
                #pragma unroll
                for (int s2 = 8; s2 > 0; s2 >>= 1)
                    #pragma unroll
                    for (int r = 0; r < s2; ++r) mx[r] = fmaxf(mx[r], mx[r + s2]);
                const float tm = fmaxf(mx[0], __shfl_xor(mx[0], 32));

                // rescale (exact skip when no lane has a new max)
                if (!__all(tm <= mrow)) {
                    const float mnew = fmaxf(mrow, tm);
                    const float corr = hw_exp2(mrow - mnew);
                    lrow *= corr;
                    #pragma unroll
                    for (int r = 0; r < 16; ++r) { oacc[0][r] *= corr; oacc[1][r] *= corr; }
                    mrow = mnew;
                }

                // p = exp2(s - m); tree row-sum for this half
                float sm[16];
                #pragma unroll
                for (int sub = sA; sub <= sB; ++sub)
                    #pragma unroll
                    for (int r = 0; r < 16; ++r)
                        sacc[sub][r] = hw_exp2(sacc[sub][r] - mrow);
                #pragma unroll
                for (int r = 0; r < 16; ++r) sm[r] = sacc[sA][r] + sacc[sB][r];
                #pragma unroll
                for (int s2 = 8; s2 > 0; s2 >>= 1)
                    #pragma unroll
                    for (int r = 0; r < s2; ++r) sm[r] += sm[r + s2];
                lrow += sm[0] + __shfl_xor(sm[0], 32);

                // per sub: pack P and O^T += V^T @ P^T (V frags scoped)
                #pragma unroll
                for (int sub = sA; sub <= sB; ++sub) {
                    u32 wpk[8];
                    #pragma unroll
                    for (int i = 0; i < 8; ++i)
                        wpk[i] = cvtpk_bf16(sacc[sub][2 * i], sacc[sub][2 * i + 1]);
                    u32 a0 = wpk[0], b0 = wpk[2];
                    u32 a1 = wpk[1], b1 = wpk[3];
                    u32 a2 = wpk[4], b2 = wpk[6];
                    u32 a3 = wpk[5], b3 = wpk[7];
                    asm("v_permlane32_swap_b32 %0, %1" : "+v"(a0), "+v"(b0));
                    asm("v_permlane32_swap_b32 %0, %1" : "+v"(a1), "+v"(b1));
                    asm("v_permlane32_swap_b32 %0, %1" : "+v"(a2), "+v"(b2));
                    asm("v_permlane32_swap_b32 %0, %1" : "+v"(a3), "+v"(b3));
                    u32x4 pw0, pw1;
                    pw0[0] = a0; pw0[1] = a1; pw0[2] = b0; pw0[3] = b1;
                    pw1[0] = a2; pw1[1] = a3; pw1[2] = b2; pw1[3] = b3;
                    const bf16x8 pb0 = __builtin_bit_cast(bf16x8, pw0);
                    const bf16x8 pb1 = __builtin_bit_cast(bf16x8, pw1);
                    __builtin_amdgcn_s_setprio(1);
                    #pragma unroll
                    for (int dt = 0; dt < 2; ++dt) {
                        const int rV = dt * 32 + lq;
                        const int jx = lq & 15;
                        const bf16x8 v0 = *reinterpret_cast<const bf16x8*>(
                            &Vc[rV * 128 + (((sub * 4 + 0 * 2 + hi) ^ jx) * 8)]);
                        oacc[dt] = __builtin_amdgcn_mfma_f32_32x32x16_bf16(
                            v0, pb0, oacc[dt], 0, 0, 0);
                        const bf16x8 v1 = *reinterpret_cast<const bf16x8*>(
                            &Vc[rV * 128 + (((sub * 4 + 1 * 2 + hi) ^ jx) * 8)]);
                        oacc[dt] = __builtin_amdgcn_mfma_f32_32x32x16_bf16(
                            v1, pb1, oacc[dt], 0, 0, 0);
                    }
                    __builtin_amdgcn_s_setprio(0);
                }
            }
        }
        __builtin_amdgcn_s_barrier();
        cur ^= 1;
    }

    // ---- epilogue: O^T / l -> AO[q][d] (lane's own q row) ----
    const float inv = 1.f / lrow;
    ushort* aorow = AO + (size_t)(b * S_ + qg) * 1024 + h * 64;
    #pragma unroll
    for (int dt = 0; dt < 2; ++dt)
        #pragma unroll
        for (int g = 0; g < 4; ++g) {
            const int d0 = dt * 32 + g * 8 + hi * 4;
            ushort4v pk;
            #pragma unroll
            for (int j = 0; j < 4; ++j) pk[j] = f2bf(oacc[dt][g * 4 + j] * inv);
            *reinterpret_cast<ushort4v*>(&aorow[d0]) = pk;
        }
}

// ---------------------------------------------------------------------------
extern "C" void kernel_launch(void* const* d_in, const int* in_sizes, int n_in,
                              void* d_out, int out_size, void* d_ws, size_t ws_size,
                              hipStream_t stream)
{
    const float* x  = (const float*)d_in[0];
    const float* Wq = (const float*)d_in[2];
    const float* bq = (const float*)d_in[3];
    const float* Wk = (const float*)d_in[4];
    const float* bk = (const float*)d_in[5];
    const float* Wv = (const float*)d_in[6];
    const float* bv = (const float*)d_in[7];
    const float* Wo = (const float*)d_in[8];
    const float* bo = (const float*)d_in[9];
    float* out = (float*)d_out;

    const size_t tok = (size_t)B_ * S_;            // 4096
    ushort* xb    = (ushort*)d_ws;                 // 4M elems
    ushort* WtQKV = xb + tok * E_;                 // 3M
    ushort* WtO   = WtQKV + (size_t)3072 * 1024;   // 1M
    ushort* Qb    = WtO + (size_t)1024 * 1024;     // 4M
    ushort* Kb    = Qb + tok * E_;                 // 4M
    ushort* Vt    = Kb + tok * E_;                 // 4M
    ushort* AO    = Vt + tok * E_;                 // 4M

    cast_x<<<2048, 256, 0, stream>>>(x, xb);
    castT_w<<<dim3(32, 16, 4), 256, 0, stream>>>(Wq, Wk, Wv, Wo, WtQKV, WtO);

    gemm_qkv<<<dim3(24, 32), 256, 0, stream>>>(xb, WtQKV, bq, bk, bv, Qb, Kb, Vt);

    attn13<<<512, 256, 0, stream>>>(Qb, Kb, Vt, AO);

    gemm_out<<<dim3(8, 32), 256, 0, stream>>>(AO, WtO, bo, out, 1024, 1024);
}

// Round 18
// 108.683 us; speedup vs baseline: 1.0837x; 1.0837x over previous
//
#include <hip/hip_runtime.h>
#include <cmath>

#define B_ 2
#define S_ 2048
#define E_ 1024
#define H_ 16
#define D_ 64

typedef __attribute__((ext_vector_type(8)))  short  bf16x8;
typedef __attribute__((ext_vector_type(4)))  float  f32x4;
typedef __attribute__((ext_vector_type(16))) float  f32x16;
typedef __attribute__((ext_vector_type(8)))  unsigned short ushort8;
typedef __attribute__((ext_vector_type(4)))  unsigned short ushort4v;
typedef __attribute__((ext_vector_type(4)))  unsigned int   u32x4;
typedef unsigned int u32;

__device__ __forceinline__ ushort f2bf(float f) {
    u32 u = __float_as_uint(f);
    u32 r = (u + 0x7fffu + ((u >> 16) & 1u)) >> 16;
    return (ushort)r;
}
__device__ __forceinline__ void gload_lds16(const ushort* gp, ushort* lp) {
    auto g = (const __attribute__((address_space(1))) u32*)gp;
    auto l = (__attribute__((address_space(3))) u32*)lp;
    __builtin_amdgcn_global_load_lds(g, l, 16, 0, 0);
}
__device__ __forceinline__ u32 cvtpk_bf16(float lo, float hi) {
    u32 r;
    asm("v_cvt_pk_bf16_f32 %0, %1, %2" : "=v"(r) : "v"(lo), "v"(hi));
    return r;
}
// raw v_exp_f32 (2^x); input always <= 0 here, hw handles -inf -> 0
__device__ __forceinline__ float hw_exp2(float x) {
    float r;
    asm("v_exp_f32 %0, %1" : "=v"(r) : "v"(x));
    return r;
}
// hardware sin/cos of (2*pi*rev); v_fract first keeps input in-domain
__device__ __forceinline__ void hw_sincos_rev(float rev, float* sn, float* cs) {
    float fr;
    asm("v_fract_f32 %0, %1" : "=v"(fr) : "v"(rev));
    asm("v_sin_f32 %0, %1" : "=v"(*sn) : "v"(fr));
    asm("v_cos_f32 %0, %1" : "=v"(*cs) : "v"(fr));
}

// ---------------------------------------------------------------------------
// cast x (f32 -> bf16), 8 elems/thread
// ---------------------------------------------------------------------------
__global__ __launch_bounds__(256) void cast_x(const float* __restrict__ in,
                                              ushort* __restrict__ out) {
    const int idx = blockIdx.x * 256 + threadIdx.x;
    const float4 a = *reinterpret_cast<const float4*>(&in[(size_t)idx * 8]);
    const float4 b = *reinterpret_cast<const float4*>(&in[(size_t)idx * 8 + 4]);
    ushort8 o;
    o[0] = f2bf(a.x); o[1] = f2bf(a.y); o[2] = f2bf(a.z); o[3] = f2bf(a.w);
    o[4] = f2bf(b.x); o[5] = f2bf(b.y); o[6] = f2bf(b.z); o[7] = f2bf(b.w);
    *reinterpret_cast<ushort8*>(&out[(size_t)idx * 8]) = o;
}

// ---------------------------------------------------------------------------
// cast + transpose weights: W[k][n] f32 -> Wt[n][k] bf16  (1024x1024 each).
// 64-k tiles + packed u32 stores (2 bf16 per store, coalesced).
// ---------------------------------------------------------------------------
__global__ __launch_bounds__(256) void castT_w(
    const float* __restrict__ Wq, const float* __restrict__ Wk,
    const float* __restrict__ Wv, const float* __restrict__ Wo,
    ushort* __restrict__ WtQKV, ushort* __restrict__ WtO)
{
    __shared__ float tile[64][33];
    const float* src; ushort* dst;
    switch (blockIdx.z) {
        case 0:  src = Wq; dst = WtQKV;                 break;
        case 1:  src = Wk; dst = WtQKV + 1024 * 1024;   break;
        case 2:  src = Wv; dst = WtQKV + 2048 * 1024;   break;
        default: src = Wo; dst = WtO;                   break;
    }
    const int k0 = blockIdx.y * 64, n0 = blockIdx.x * 32;
    const int tn = threadIdx.x & 31, tk = threadIdx.x >> 5;   // 0..31, 0..7
    #pragma unroll
    for (int p = 0; p < 8; ++p)
        tile[p * 8 + tk][tn] = src[(size_t)(k0 + p * 8 + tk) * 1024 + n0 + tn];
    __syncthreads();
    const int kp = (threadIdx.x & 31) * 2, nq = threadIdx.x >> 5;
    #pragma unroll
    for (int q = 0; q < 4; ++q) {
        const int n = q * 8 + nq;
        const u32 v = (u32)f2bf(tile[kp][n]) | ((u32)f2bf(tile[kp + 1][n]) << 16);
        *reinterpret_cast<u32*>(&dst[(size_t)(n0 + n) * 1024 + k0 + kp]) = v;
    }
}

// ---------------------------------------------------------------------------
// QKV GEMM (M=4096, N=3072, K=1024), 128x128 tile, BK=64, T2-swizzled LDS.
// SINGLE-buffered (r17 lesson: dbuf's 64 KB dropped occupancy 3->2 blocks/CU
// + 256-block tail wave => regression.  At 3 blocks/CU the cross-block TLP
// already hides the per-step drain).  Epilogue fuses bias + RoPE; Q scaled
// by 0.125*log2(e).  Writes Q->Qb, K->Kb (row-major), V->Vt (transposed).
// ---------------------------------------------------------------------------
__global__ __launch_bounds__(256, 3) void gemm_qkv(
    const ushort* __restrict__ A, const ushort* __restrict__ Bt,
    const float* __restrict__ bq, const float* __restrict__ bk,
    const float* __restrict__ bv,
    ushort* __restrict__ Qb, ushort* __restrict__ Kb, ushort* __restrict__ Vt)
{
    __shared__ ushort As[128 * 64];
    __shared__ ushort Bs[128 * 64];
    const int t = threadIdx.x, w = t >> 6, l = t & 63;
    const int lr = l & 15, lg = l >> 4;
    const int wr = w >> 1, wc = w & 1;
    const int row0 = blockIdx.y * 128, col0 = blockIdx.x * 128;

    f32x4 acc[4][4] = {};

    for (int k0 = 0; k0 < 1024; k0 += 64) {
        #pragma unroll
        for (int i = 0; i < 4; ++i) {
            const int r  = w * 32 + i * 8 + (l >> 3);
            const int cs = ((l & 7) ^ (r & 7)) * 8;          // src pre-swizzle
            gload_lds16(&A [(size_t)(row0 + r) * 1024 + k0 + cs], &As[(w * 32 + i * 8) * 64]);
            gload_lds16(&Bt[(size_t)(col0 + r) * 1024 + k0 + cs], &Bs[(w * 32 + i * 8) * 64]);
        }
        asm volatile("s_waitcnt vmcnt(0)");
        __syncthreads();

        #pragma unroll
        for (int kk = 0; kk < 2; ++kk) {
            bf16x8 af[4], bfr[4];
            #pragma unroll
            for (int m = 0; m < 4; ++m)
                af[m] = *reinterpret_cast<const bf16x8*>(
                    &As[(wr * 64 + m * 16 + lr) * 64 + (((kk * 4 + lg) ^ (lr & 7)) * 8)]);
            #pragma unroll
            for (int n = 0; n < 4; ++n)
                bfr[n] = *reinterpret_cast<const bf16x8*>(
                    &Bs[(wc * 64 + n * 16 + lr) * 64 + (((kk * 4 + lg) ^ (lr & 7)) * 8)]);
            #pragma unroll
            for (int m = 0; m < 4; ++m)
                #pragma unroll
                for (int n = 0; n < 4; ++n)
                    acc[m][n] = __builtin_amdgcn_mfma_f32_16x16x32_bf16(
                        af[m], bfr[n], acc[m][n], 0, 0, 0);
        }
        __syncthreads();
    }

    const int cbase = col0 + wc * 64;          // wave's 64-col span (one head)
    const int cls   = cbase >> 10;             // 0=Q, 1=K, 2=V
    const int hcol  = cbase & 1023;            // head-aligned col within 1024
    const float* bias = (cls == 0) ? bq : (cls == 1 ? bk : bv);

    if (cls < 2) {
        ushort* dst = (cls == 0) ? Qb : Kb;
        const float qscale = (cls == 0) ? 0.1803368801f : 1.0f;  // 0.125*log2(e)
        #pragma unroll
        for (int m = 0; m < 4; ++m) {
            const int rbase = row0 + wr * 64 + m * 16 + lg * 4;
            #pragma unroll
            for (int n = 0; n < 2; ++n) {
                const int i    = n * 16 + lr;                  // 0..31
                const float b0 = bias[hcol + i];
                const float b1 = bias[hcol + i + 32];
                // invf / (2*pi): angle in revolutions = s * invf_rev
                const float invf_rev =
                    exp2f(-(float)i * 0.415241012f) * 0.15915494309f;
                #pragma unroll
                for (int r = 0; r < 4; ++r) {
                    const int row = rbase + r;
                    const int s   = row & (S_ - 1);
                    float sn, cs_;
                    hw_sincos_rev((float)s * invf_rev, &sn, &cs_);
                    const float v0 = acc[m][n][r]     + b0;
                    const float v1 = acc[m][n + 2][r] + b1;
                    dst[(size_t)row * 1024 + hcol + i]      = f2bf((v0 * cs_ - v1 * sn) * qscale);
                    dst[(size_t)row * 1024 + hcol + i + 32] = f2bf((v1 * cs_ + v0 * sn) * qscale);
                }
            }
        }
    } else {
        const int h = hcol >> 6;
        #pragma unroll
        for (int m = 0; m < 4; ++m) {
            const int rbase = row0 + wr * 64 + m * 16 + lg * 4;
            const int bb = rbase >> 11, s0 = rbase & (S_ - 1);
            #pragma unroll
            for (int n = 0; n < 4; ++n) {
                const int d = n * 16 + lr;
                const float bia = bias[hcol + d];
                ushort4v pk;
                #pragma unroll
                for (int r = 0; r < 4; ++r) pk[r] = f2bf(acc[m][n][r] + bia);
                *reinterpret_cast<ushort4v*>(
                    &Vt[((size_t)(bb * 16 + h) * 64 + d) * S_ + s0]) = pk;
            }
        }
    }
}

// ---------------------------------------------------------------------------
// Output GEMM: C[M,1024] f32 = A @ Wt^T + bias.  Dbuf + counted vmcnt(8) +
// raw s_barrier (verified win r12; 1 block/CU so no TLP to lose).
// ---------------------------------------------------------------------------
__global__ __launch_bounds__(256, 1) void gemm_out(
    const ushort* __restrict__ A, const ushort* __restrict__ Bt,
    const float* __restrict__ bias, float* __restrict__ C, int N, int K)
{
    __shared__ ushort As[2][128 * 64];
    __shared__ ushort Bs[2][128 * 64];
    const int t = threadIdx.x, w = t >> 6, l = t & 63;
    const int lr = l & 15, lg = l >> 4;
    const int wr = w >> 1, wc = w & 1;
    const int row0 = blockIdx.y * 128, col0 = blockIdx.x * 128;

    f32x4 acc[4][4] = {};

    auto STAGE = [&](int buf, int k0) {
        #pragma unroll
        for (int i = 0; i < 4; ++i) {
            const int r  = w * 32 + i * 8 + (l >> 3);
            const int cs = ((l & 7) ^ (r & 7)) * 8;
            gload_lds16(&A [(size_t)(row0 + r) * K + k0 + cs], &As[buf][(w * 32 + i * 8) * 64]);
            gload_lds16(&Bt[(size_t)(col0 + r) * K + k0 + cs], &Bs[buf][(w * 32 + i * 8) * 64]);
        }
    };

    STAGE(0, 0);
    int cur = 0;

    for (int k0 = 0; k0 < K; k0 += 64) {
        if (k0 + 64 < K) {
            STAGE(cur ^ 1, k0 + 64);
            asm volatile("s_waitcnt vmcnt(8)" ::: "memory");
        } else {
            asm volatile("s_waitcnt vmcnt(0)" ::: "memory");
        }
        __builtin_amdgcn_s_barrier();

        #pragma unroll
        for (int kk = 0; kk < 2; ++kk) {
            bf16x8 af[4], bfr[4];
            #pragma unroll
            for (int m = 0; m < 4; ++m)
                af[m] = *reinterpret_cast<const bf16x8*>(
                    &As[cur][(wr * 64 + m * 16 + lr) * 64 + (((kk * 4 + lg) ^ (lr & 7)) * 8)]);
            #pragma unroll
            for (int n = 0; n < 4; ++n)
                bfr[n] = *reinterpret_cast<const bf16x8*>(
                    &Bs[cur][(wc * 64 + n * 16 + lr) * 64 + (((kk * 4 + lg) ^ (lr & 7)) * 8)]);
            #pragma unroll
            for (int m = 0; m < 4; ++m)
                #pragma unroll
                for (int n = 0; n < 4; ++n)
                    acc[m][n] = __builtin_amdgcn_mfma_f32_16x16x32_bf16(
                        af[m], bfr[n], acc[m][n], 0, 0, 0);
        }
        __builtin_amdgcn_s_barrier();
        cur ^= 1;
    }

    #pragma unroll
    for (int m = 0; m < 4; ++m) {
        const int rbase = row0 + wr * 64 + m * 16 + lg * 4;
        #pragma unroll
        for (int n = 0; n < 4; ++n) {
            const int c = col0 + wc * 64 + n * 16 + lr;
            const float bv = bias[c];
            #pragma unroll
            for (int r = 0; r < 4; ++r)
                C[(size_t)(rbase + r) * N + c] = acc[m][n][r] + bv;
        }
    }
}

// ---------------------------------------------------------------------------
// attn13 (kept): KVBLK=128, balanced CU pairs, split online softmax
// (2 sequential 64-key flash updates per tile), in-register machinery.
// ---------------------------------------------------------------------------
__global__ __launch_bounds__(256, 2) void attn13(
    const ushort* __restrict__ Qb, const ushort* __restrict__ Kb,
    const ushort* __restrict__ Vt, ushort* __restrict__ AO)
{
    __shared__ ushort Ks[2][128 * 64];
    __shared__ ushort Vs[2][64 * 128];

    const int t = threadIdx.x, w = t >> 6, l = t & 63;
    const int lq = l & 31, hi = l >> 5;
    const int idx = blockIdx.x;
    const int bh = idx & 31, b = bh >> 4, h = bh & 15;
    const int g8 = idx >> 5;                   // 0..15
    const int qb = (idx < 256) ? (15 - g8) : (g8 - 8);   // balanced CU pairs
    const int q0 = qb * 128, qw = q0 + w * 32;
    const int qg = qw + lq;                    // this lane's q row

    const ushort* Kbh = Kb + (size_t)b * S_ * 1024 + h * 64;
    const ushort* Vbh = Vt + (size_t)bh * 64 * S_;

    // Q fragments (B-operand): qf[dc] = Q[qg][16*dc + 8*hi + j]
    bf16x8 qf[4];
    {
        const ushort* qrow = Qb + (size_t)(b * S_ + qg) * 1024 + h * 64 + 8 * hi;
        #pragma unroll
        for (int dc = 0; dc < 4; ++dc)
            qf[dc] = *reinterpret_cast<const bf16x8*>(qrow + 16 * dc);
    }

    f32x16 oacc[2] = {};                       // O^T: rows=d, col=q(lane)
    float mrow = -3.0e38f, lrow = 0.f;

    auto STAGE = [&](int buf, int kt) {
        // K: 128 keys x 64 d, 16 KB -> 4 instrs.  Linear dest, pre-swizzled src.
        #pragma unroll
        for (int i = 0; i < 4; ++i) {
            const int cid = i * 256 + t;                     // 0..1023
            const int r   = cid >> 3;                        // key 0..127
            const int cs  = ((cid & 7) ^ (r & 7)) * 8;
            const int db  = (i * 256 + w * 64) * 8;          // wave-uniform dest
            gload_lds16(&Kbh[(size_t)(kt + r) * 1024 + cs], &Ks[buf][db]);
        }
        // V: 64 d x 128 keys, 16 KB -> 4 instrs.  16-chunk XOR swizzle.
        #pragma unroll
        for (int i = 0; i < 4; ++i) {
            const int cid = i * 256 + t;
            const int d   = cid >> 4;                        // 0..63
            const int cs  = ((cid & 15) ^ (d & 15)) * 8;
            const int db  = (i * 256 + w * 64) * 8;
            gload_lds16(&Vbh[(size_t)d * S_ + kt + cs], &Vs[buf][db]);
        }
    };

    const int kend = q0 + 128;
    STAGE(0, 0);
    int cur = 0;

    for (int kt = 0; kt < kend; kt += 128) {
        if (kt + 128 < kend) {
            STAGE(cur ^ 1, kt + 128);
            asm volatile("s_waitcnt vmcnt(8)" ::: "memory");  // current tile only
        } else {
            asm volatile("s_waitcnt vmcnt(0)" ::: "memory");
        }
        __builtin_amdgcn_s_barrier();

        {
            const ushort* Kc = &Ks[cur][0];
            const ushort* Vc = &Vs[cur][0];

            // ---- S^T = K @ Q^T over 128 keys: all 4 subs ISSUED up front ----
            f32x16 sacc[4] = {};
            __builtin_amdgcn_s_setprio(1);
            #pragma unroll
            for (int sub = 0; sub < 4; ++sub) {
                const int rK = sub * 32 + lq;
                const int rx = lq & 7;
                #pragma unroll
                for (int dc = 0; dc < 4; ++dc) {
                    const bf16x8 kf = *reinterpret_cast<const bf16x8*>(
                        &Kc[rK * 64 + (((2 * dc + hi) ^ rx) * 8)]);
                    sacc[sub] = __builtin_amdgcn_mfma_f32_32x32x16_bf16(
                        kf, qf[dc], sacc[sub], 0, 0, 0);
                }
            }
            __builtin_amdgcn_s_setprio(0);

            // ---- two sequential 64-key online-softmax updates ----
            #pragma unroll
            for (int hf = 0; hf < 2; ++hf) {
                const int sA = 2 * hf, sB = 2 * hf + 1;

                // causal mask (boundary subs only; full-masked subs -> p=0)
                #pragma unroll
                for (int sub = sA; sub <= sB; ++sub)
                    if (kt + sub * 32 + 31 > qw) {
                        #pragma unroll
                        for (int r = 0; r < 16; ++r) {
                            const int kg = kt + sub * 32 + (r & 3) + 8 * (r >> 2) + 4 * hi;
                            if (kg > qg) sacc[sub][r] = -1.0e30f;
                        }
                    }

                // row max over this half's 64 scores: tree + cross-half swap
                float mx[16];
                #pragma unroll
                for (int r = 0; r < 16; ++r)
                    mx[r] = fmaxf(sacc[sA][r], sacc[sB][r]);
                #pragma unroll
                for (int s2 = 8; s2 > 0; s2 >>= 1)
                    #pragma unroll
                    for (int r = 0; r < s2; ++r) mx[r] = fmaxf(mx[r], mx[r + s2]);
                const float tm = fmaxf(mx[0], __shfl_xor(mx[0], 32));

                // rescale (exact skip when no lane has a new max)
                if (!__all(tm <= mrow)) {
                    const float mnew = fmaxf(mrow, tm);
                    const float corr = hw_exp2(mrow - mnew);
                    lrow *= corr;
                    #pragma unroll
                    for (int r = 0; r < 16; ++r) { oacc[0][r] *= corr; oacc[1][r] *= corr; }
                    mrow = mnew;
                }

                // p = exp2(s - m); tree row-sum for this half
                float sm[16];
                #pragma unroll
                for (int sub = sA; sub <= sB; ++sub)
                    #pragma unroll
                    for (int r = 0; r < 16; ++r)
                        sacc[sub][r] = hw_exp2(sacc[sub][r] - mrow);
                #pragma unroll
                for (int r = 0; r < 16; ++r) sm[r] = sacc[sA][r] + sacc[sB][r];
                #pragma unroll
                for (int s2 = 8; s2 > 0; s2 >>= 1)
                    #pragma unroll
                    for (int r = 0; r < s2; ++r) sm[r] += sm[r + s2];
                lrow += sm[0] + __shfl_xor(sm[0], 32);

                // per sub: pack P and O^T += V^T @ P^T (V frags scoped)
                #pragma unroll
                for (int sub = sA; sub <= sB; ++sub) {
                    u32 wpk[8];
                    #pragma unroll
                    for (int i = 0; i < 8; ++i)
                        wpk[i] = cvtpk_bf16(sacc[sub][2 * i], sacc[sub][2 * i + 1]);
                    u32 a0 = wpk[0], b0 = wpk[2];
                    u32 a1 = wpk[1], b1 = wpk[3];
                    u32 a2 = wpk[4], b2 = wpk[6];
                    u32 a3 = wpk[5], b3 = wpk[7];
                    asm("v_permlane32_swap_b32 %0, %1" : "+v"(a0), "+v"(b0));
                    asm("v_permlane32_swap_b32 %0, %1" : "+v"(a1), "+v"(b1));
                    asm("v_permlane32_swap_b32 %0, %1" : "+v"(a2), "+v"(b2));
                    asm("v_permlane32_swap_b32 %0, %1" : "+v"(a3), "+v"(b3));
                    u32x4 pw0, pw1;
                    pw0[0] = a0; pw0[1] = a1; pw0[2] = b0; pw0[3] = b1;
                    pw1[0] = a2; pw1[1] = a3; pw1[2] = b2; pw1[3] = b3;
                    const bf16x8 pb0 = __builtin_bit_cast(bf16x8, pw0);
                    const bf16x8 pb1 = __builtin_bit_cast(bf16x8, pw1);
                    __builtin_amdgcn_s_setprio(1);
                    #pragma unroll
                    for (int dt = 0; dt < 2; ++dt) {
                        const int rV = dt * 32 + lq;
                        const int jx = lq & 15;
                        const bf16x8 v0 = *reinterpret_cast<const bf16x8*>(
                            &Vc[rV * 128 + (((sub * 4 + 0 * 2 + hi) ^ jx) * 8)]);
                        oacc[dt] = __builtin_amdgcn_mfma_f32_32x32x16_bf16(
                            v0, pb0, oacc[dt], 0, 0, 0);
                        const bf16x8 v1 = *reinterpret_cast<const bf16x8*>(
                            &Vc[rV * 128 + (((sub * 4 + 1 * 2 + hi) ^ jx) * 8)]);
                        oacc[dt] = __builtin_amdgcn_mfma_f32_32x32x16_bf16(
                            v1, pb1, oacc[dt], 0, 0, 0);
                    }
                    __builtin_amdgcn_s_setprio(0);
                }
            }
        }
        __builtin_amdgcn_s_barrier();
        cur ^= 1;
    }

    // ---- epilogue: O^T / l -> AO[q][d] (lane's own q row) ----
    const float inv = 1.f / lrow;
    ushort* aorow = AO + (size_t)(b * S_ + qg) * 1024 + h * 64;
    #pragma unroll
    for (int dt = 0; dt < 2; ++dt)
        #pragma unroll
        for (int g = 0; g < 4; ++g) {
            const int d0 = dt * 32 + g * 8 + hi * 4;
            ushort4v pk;
            #pragma unroll
            for (int j = 0; j < 4; ++j) pk[j] = f2bf(oacc[dt][g * 4 + j] * inv);
            *reinterpret_cast<ushort4v*>(&aorow[d0]) = pk;
        }
}

// ---------------------------------------------------------------------------
extern "C" void kernel_launch(void* const* d_in, const int* in_sizes, int n_in,
                              void* d_out, int out_size, void* d_ws, size_t ws_size,
                              hipStream_t stream)
{
    const float* x  = (const float*)d_in[0];
    const float* Wq = (const float*)d_in[2];
    const float* bq = (const float*)d_in[3];
    const float* Wk = (const float*)d_in[4];
    const float* bk = (const float*)d_in[5];
    const float* Wv = (const float*)d_in[6];
    const float* bv = (const float*)d_in[7];
    const float* Wo = (const float*)d_in[8];
    const float* bo = (const float*)d_in[9];
    float* out = (float*)d_out;

    const size_t tok = (size_t)B_ * S_;            // 4096
    ushort* xb    = (ushort*)d_ws;                 // 4M elems
    ushort* WtQKV = xb + tok * E_;                 // 3M
    ushort* WtO   = WtQKV + (size_t)3072 * 1024;   // 1M
    ushort* Qb    = WtO + (size_t)1024 * 1024;     // 4M
    ushort* Kb    = Qb + tok * E_;                 // 4M
    ushort* Vt    = Kb + tok * E_;                 // 4M
    ushort* AO    = Vt + tok * E_;                 // 4M

    cast_x<<<2048, 256, 0, stream>>>(x, xb);
    castT_w<<<dim3(32, 16, 4), 256, 0, stream>>>(Wq, Wk, Wv, Wo, WtQKV, WtO);

    gemm_qkv<<<dim3(24, 32), 256, 0, stream>>>(xb, WtQKV, bq, bk, bv, Qb, Kb, Vt);

    attn13<<<512, 256, 0, stream>>>(Qb, Kb, Vt, AO);

    gemm_out<<<dim3(8, 32), 256, 0, stream>>>(AO, WtO, bo, out, 1024, 1024);
}

// Round 19
// 108.369 us; speedup vs baseline: 1.0869x; 1.0029x over previous
//
#include <hip/hip_runtime.h>
#include <cmath>

#define B_ 2
#define S_ 2048
#define E_ 1024
#define H_ 16
#define D_ 64

typedef __attribute__((ext_vector_type(8)))  short  bf16x8;
typedef __attribute__((ext_vector_type(4)))  float  f32x4;
typedef __attribute__((ext_vector_type(16))) float  f32x16;
typedef __attribute__((ext_vector_type(8)))  unsigned short ushort8;
typedef __attribute__((ext_vector_type(4)))  unsigned short ushort4v;
typedef __attribute__((ext_vector_type(4)))  unsigned int   u32x4;
typedef unsigned int u32;

__device__ __forceinline__ ushort f2bf(float f) {
    u32 u = __float_as_uint(f);
    u32 r = (u + 0x7fffu + ((u >> 16) & 1u)) >> 16;
    return (ushort)r;
}
__device__ __forceinline__ void gload_lds16(const ushort* gp, ushort* lp) {
    auto g = (const __attribute__((address_space(1))) u32*)gp;
    auto l = (__attribute__((address_space(3))) u32*)lp;
    __builtin_amdgcn_global_load_lds(g, l, 16, 0, 0);
}
__device__ __forceinline__ u32 cvtpk_bf16(float lo, float hi) {
    u32 r;
    asm("v_cvt_pk_bf16_f32 %0, %1, %2" : "=v"(r) : "v"(lo), "v"(hi));
    return r;
}
// raw v_exp_f32 (2^x); input always <= 0 here, hw handles -inf -> 0
__device__ __forceinline__ float hw_exp2(float x) {
    float r;
    asm("v_exp_f32 %0, %1" : "=v"(r) : "v"(x));
    return r;
}
// hardware sin/cos of (2*pi*rev); v_fract first keeps input in-domain
__device__ __forceinline__ void hw_sincos_rev(float rev, float* sn, float* cs) {
    float fr;
    asm("v_fract_f32 %0, %1" : "=v"(fr) : "v"(rev));
    asm("v_sin_f32 %0, %1" : "=v"(*sn) : "v"(fr));
    asm("v_cos_f32 %0, %1" : "=v"(*cs) : "v"(fr));
}

// ---------------------------------------------------------------------------
// cast x (f32 -> bf16), 8 elems/thread
// ---------------------------------------------------------------------------
__global__ __launch_bounds__(256) void cast_x(const float* __restrict__ in,
                                              ushort* __restrict__ out) {
    const int idx = blockIdx.x * 256 + threadIdx.x;
    const float4 a = *reinterpret_cast<const float4*>(&in[(size_t)idx * 8]);
    const float4 b = *reinterpret_cast<const float4*>(&in[(size_t)idx * 8 + 4]);
    ushort8 o;
    o[0] = f2bf(a.x); o[1] = f2bf(a.y); o[2] = f2bf(a.z); o[3] = f2bf(a.w);
    o[4] = f2bf(b.x); o[5] = f2bf(b.y); o[6] = f2bf(b.z); o[7] = f2bf(b.w);
    *reinterpret_cast<ushort8*>(&out[(size_t)idx * 8]) = o;
}

// ---------------------------------------------------------------------------
// cast + transpose weights: W[k][n] f32 -> Wt[n][k] bf16  (1024x1024 each).
// 64-k tiles + packed u32 stores (2 bf16 per store, coalesced).
// ---------------------------------------------------------------------------
__global__ __launch_bounds__(256) void castT_w(
    const float* __restrict__ Wq, const float* __restrict__ Wk,
    const float* __restrict__ Wv, const float* __restrict__ Wo,
    ushort* __restrict__ WtQKV, ushort* __restrict__ WtO)
{
    __shared__ float tile[64][33];
    const float* src; ushort* dst;
    switch (blockIdx.z) {
        case 0:  src = Wq; dst = WtQKV;                 break;
        case 1:  src = Wk; dst = WtQKV + 1024 * 1024;   break;
        case 2:  src = Wv; dst = WtQKV + 2048 * 1024;   break;
        default: src = Wo; dst = WtO;                   break;
    }
    const int k0 = blockIdx.y * 64, n0 = blockIdx.x * 32;
    const int tn = threadIdx.x & 31, tk = threadIdx.x >> 5;   // 0..31, 0..7
    #pragma unroll
    for (int p = 0; p < 8; ++p)
        tile[p * 8 + tk][tn] = src[(size_t)(k0 + p * 8 + tk) * 1024 + n0 + tn];
    __syncthreads();
    const int kp = (threadIdx.x & 31) * 2, nq = threadIdx.x >> 5;
    #pragma unroll
    for (int q = 0; q < 4; ++q) {
        const int n = q * 8 + nq;
        const u32 v = (u32)f2bf(tile[kp][n]) | ((u32)f2bf(tile[kp + 1][n]) << 16);
        *reinterpret_cast<u32*>(&dst[(size_t)(n0 + n) * 1024 + k0 + kp]) = v;
    }
}

// ---------------------------------------------------------------------------
// QKV GEMM (M=4096, N=3072, K=1024), 128x128 tile, BK=64, T2-swizzled LDS.
// Single-buffered (r17 lesson).  r18: T1 XCD-grouping block swizzle —
// hardware linear id lin = y*24+x dispatches XCD = lin%8; remap so XCD j
// owns row-panels 4j..4j+3 (1 MB of A, L2-resident across all 24 column
// reuses) instead of a scattered set that thrashes both operands through L3.
// Bijective: lin = slot*8+xcd <-> (row = xcd*4 + slot/24, col = slot%24).
// Epilogue fuses bias + RoPE; Q scaled by 0.125*log2(e).
// Writes Q->Qb, K->Kb (row-major), V->Vt (transposed).
// ---------------------------------------------------------------------------
__global__ __launch_bounds__(256, 3) void gemm_qkv(
    const ushort* __restrict__ A, const ushort* __restrict__ Bt,
    const float* __restrict__ bq, const float* __restrict__ bk,
    const float* __restrict__ bv,
    ushort* __restrict__ Qb, ushort* __restrict__ Kb, ushort* __restrict__ Vt)
{
    __shared__ ushort As[128 * 64];
    __shared__ ushort Bs[128 * 64];
    const int t = threadIdx.x, w = t >> 6, l = t & 63;
    const int lr = l & 15, lg = l >> 4;
    const int wr = w >> 1, wc = w & 1;

    // T1 XCD-grouping swizzle (bijective, 768 % 8 == 0)
    const int lin  = blockIdx.y * 24 + blockIdx.x;   // hw dispatch linear id
    const int xcd  = lin & 7;
    const int slot = lin >> 3;                       // 0..95
    const int row0 = (xcd * 4 + slot / 24) * 128;    // row-panel 0..31
    const int col0 = (slot % 24) * 128;              // col-panel 0..23

    f32x4 acc[4][4] = {};

    for (int k0 = 0; k0 < 1024; k0 += 64) {
        #pragma unroll
        for (int i = 0; i < 4; ++i) {
            const int r  = w * 32 + i * 8 + (l >> 3);
            const int cs = ((l & 7) ^ (r & 7)) * 8;          // src pre-swizzle
            gload_lds16(&A [(size_t)(row0 + r) * 1024 + k0 + cs], &As[(w * 32 + i * 8) * 64]);
            gload_lds16(&Bt[(size_t)(col0 + r) * 1024 + k0 + cs], &Bs[(w * 32 + i * 8) * 64]);
        }
        asm volatile("s_waitcnt vmcnt(0)");
        __syncthreads();

        #pragma unroll
        for (int kk = 0; kk < 2; ++kk) {
            bf16x8 af[4], bfr[4];
            #pragma unroll
            for (int m = 0; m < 4; ++m)
                af[m] = *reinterpret_cast<const bf16x8*>(
                    &As[(wr * 64 + m * 16 + lr) * 64 + (((kk * 4 + lg) ^ (lr & 7)) * 8)]);
            #pragma unroll
            for (int n = 0; n < 4; ++n)
                bfr[n] = *reinterpret_cast<const bf16x8*>(
                    &Bs[(wc * 64 + n * 16 + lr) * 64 + (((kk * 4 + lg) ^ (lr & 7)) * 8)]);
            #pragma unroll
            for (int m = 0; m < 4; ++m)
                #pragma unroll
                for (int n = 0; n < 4; ++n)
                    acc[m][n] = __builtin_amdgcn_mfma_f32_16x16x32_bf16(
                        af[m], bfr[n], acc[m][n], 0, 0, 0);
        }
        __syncthreads();
    }

    const int cbase = col0 + wc * 64;          // wave's 64-col span (one head)
    const int cls   = cbase >> 10;             // 0=Q, 1=K, 2=V
    const int hcol  = cbase & 1023;            // head-aligned col within 1024
    const float* bias = (cls == 0) ? bq : (cls == 1 ? bk : bv);

    if (cls < 2) {
        ushort* dst = (cls == 0) ? Qb : Kb;
        const float qscale = (cls == 0) ? 0.1803368801f : 1.0f;  // 0.125*log2(e)
        #pragma unroll
        for (int m = 0; m < 4; ++m) {
            const int rbase = row0 + wr * 64 + m * 16 + lg * 4;
            #pragma unroll
            for (int n = 0; n < 2; ++n) {
                const int i    = n * 16 + lr;                  // 0..31
                const float b0 = bias[hcol + i];
                const float b1 = bias[hcol + i + 32];
                // invf / (2*pi): angle in revolutions = s * invf_rev
                const float invf_rev =
                    exp2f(-(float)i * 0.415241012f) * 0.15915494309f;
                #pragma unroll
                for (int r = 0; r < 4; ++r) {
                    const int row = rbase + r;
                    const int s   = row & (S_ - 1);
                    float sn, cs_;
                    hw_sincos_rev((float)s * invf_rev, &sn, &cs_);
                    const float v0 = acc[m][n][r]     + b0;
                    const float v1 = acc[m][n + 2][r] + b1;
                    dst[(size_t)row * 1024 + hcol + i]      = f2bf((v0 * cs_ - v1 * sn) * qscale);
                    dst[(size_t)row * 1024 + hcol + i + 32] = f2bf((v1 * cs_ + v0 * sn) * qscale);
                }
            }
        }
    } else {
        const int h = hcol >> 6;
        #pragma unroll
        for (int m = 0; m < 4; ++m) {
            const int rbase = row0 + wr * 64 + m * 16 + lg * 4;
            const int bb = rbase >> 11, s0 = rbase & (S_ - 1);
            #pragma unroll
            for (int n = 0; n < 4; ++n) {
                const int d = n * 16 + lr;
                const float bia = bias[hcol + d];
                ushort4v pk;
                #pragma unroll
                for (int r = 0; r < 4; ++r) pk[r] = f2bf(acc[m][n][r] + bia);
                *reinterpret_cast<ushort4v*>(
                    &Vt[((size_t)(bb * 16 + h) * 64 + d) * S_ + s0]) = pk;
            }
        }
    }
}

// ---------------------------------------------------------------------------
// Output GEMM: C[M,1024] f32 = A @ Wt^T + bias.  Dbuf + counted vmcnt(8) +
// raw s_barrier (verified win r12; 1 block/CU so no TLP to lose).
// ---------------------------------------------------------------------------
__global__ __launch_bounds__(256, 1) void gemm_out(
    const ushort* __restrict__ A, const ushort* __restrict__ Bt,
    const float* __restrict__ bias, float* __restrict__ C, int N, int K)
{
    __shared__ ushort As[2][128 * 64];
    __shared__ ushort Bs[2][128 * 64];
    const int t = threadIdx.x, w = t >> 6, l = t & 63;
    const int lr = l & 15, lg = l >> 4;
    const int wr = w >> 1, wc = w & 1;
    const int row0 = blockIdx.y * 128, col0 = blockIdx.x * 128;

    f32x4 acc[4][4] = {};

    auto STAGE = [&](int buf, int k0) {
        #pragma unroll
        for (int i = 0; i < 4; ++i) {
            const int r  = w * 32 + i * 8 + (l >> 3);
            const int cs = ((l & 7) ^ (r & 7)) * 8;
            gload_lds16(&A [(size_t)(row0 + r) * K + k0 + cs], &As[buf][(w * 32 + i * 8) * 64]);
            gload_lds16(&Bt[(size_t)(col0 + r) * K + k0 + cs], &Bs[buf][(w * 32 + i * 8) * 64]);
        }
    };

    STAGE(0, 0);
    int cur = 0;

    for (int k0 = 0; k0 < K; k0 += 64) {
        if (k0 + 64 < K) {
            STAGE(cur ^ 1, k0 + 64);
            asm volatile("s_waitcnt vmcnt(8)" ::: "memory");
        } else {
            asm volatile("s_waitcnt vmcnt(0)" ::: "memory");
        }
        __builtin_amdgcn_s_barrier();

        #pragma unroll
        for (int kk = 0; kk < 2; ++kk) {
            bf16x8 af[4], bfr[4];
            #pragma unroll
            for (int m = 0; m < 4; ++m)
                af[m] = *reinterpret_cast<const bf16x8*>(
                    &As[cur][(wr * 64 + m * 16 + lr) * 64 + (((kk * 4 + lg) ^ (lr & 7)) * 8)]);
            #pragma unroll
            for (int n = 0; n < 4; ++n)
                bfr[n] = *reinterpret_cast<const bf16x8*>(
                    &Bs[cur][(wc * 64 + n * 16 + lr) * 64 + (((kk * 4 + lg) ^ (lr & 7)) * 8)]);
            #pragma unroll
            for (int m = 0; m < 4; ++m)
                #pragma unroll
                for (int n = 0; n < 4; ++n)
                    acc[m][n] = __builtin_amdgcn_mfma_f32_16x16x32_bf16(
                        af[m], bfr[n], acc[m][n], 0, 0, 0);
        }
        __builtin_amdgcn_s_barrier();
        cur ^= 1;
    }

    #pragma unroll
    for (int m = 0; m < 4; ++m) {
        const int rbase = row0 + wr * 64 + m * 16 + lg * 4;
        #pragma unroll
        for (int n = 0; n < 4; ++n) {
            const int c = col0 + wc * 64 + n * 16 + lr;
            const float bv = bias[c];
            #pragma unroll
            for (int r = 0; r < 4; ++r)
                C[(size_t)(rbase + r) * N + c] = acc[m][n][r] + bv;
        }
    }
}

// ---------------------------------------------------------------------------
// attn13 (kept): KVBLK=128, balanced CU pairs, split online softmax
// (2 sequential 64-key flash updates per tile), in-register machinery.
// ---------------------------------------------------------------------------
__global__ __launch_bounds__(256, 2) void attn13(
    const ushort* __restrict__ Qb, const ushort* __restrict__ Kb,
    const ushort* __restrict__ Vt, ushort* __restrict__ AO)
{
    __shared__ ushort Ks[2][128 * 64];
    __shared__ ushort Vs[2][64 * 128];

    const int t = threadIdx.x, w = t >> 6, l = t & 63;
    const int lq = l & 31, hi = l >> 5;
    const int idx = blockIdx.x;
    const int bh = idx & 31, b = bh >> 4, h = bh & 15;
    const int g8 = idx >> 5;                   // 0..15
    const int qb = (idx < 256) ? (15 - g8) : (g8 - 8);   // balanced CU pairs
    const int q0 = qb * 128, qw = q0 + w * 32;
    const int qg = qw + lq;                    // this lane's q row

    const ushort* Kbh = Kb + (size_t)b * S_ * 1024 + h * 64;
    const ushort* Vbh = Vt + (size_t)bh * 64 * S_;

    // Q fragments (B-operand): qf[dc] = Q[qg][16*dc + 8*hi + j]
    bf16x8 qf[4];
    {
        const ushort* qrow = Qb + (size_t)(b * S_ + qg) * 1024 + h * 64 + 8 * hi;
        #pragma unroll
        for (int dc = 0; dc < 4; ++dc)
            qf[dc] = *reinterpret_cast<const bf16x8*>(qrow + 16 * dc);
    }

    f32x16 oacc[2] = {};                       // O^T: rows=d, col=q(lane)
    float mrow = -3.0e38f, lrow = 0.f;

    auto STAGE = [&](int buf, int kt) {
        // K: 128 keys x 64 d, 16 KB -> 4 instrs.  Linear dest, pre-swizzled src.
        #pragma unroll
        for (int i = 0; i < 4; ++i) {
            const int cid = i * 256 + t;                     // 0..1023
            const int r   = cid >> 3;                        // key 0..127
            const int cs  = ((cid & 7) ^ (r & 7)) * 8;
            const int db  = (i * 256 + w * 64) * 8;          // wave-uniform dest
            gload_lds16(&Kbh[(size_t)(kt + r) * 1024 + cs], &Ks[buf][db]);
        }
        // V: 64 d x 128 keys, 16 KB -> 4 instrs.  16-chunk XOR swizzle.
        #pragma unroll
        for (int i = 0; i < 4; ++i) {
            const int cid = i * 256 + t;
            const int d   = cid >> 4;                        // 0..63
            const int cs  = ((cid & 15) ^ (d & 15)) * 8;
            const int db  = (i * 256 + w * 64) * 8;
            gload_lds16(&Vbh[(size_t)d * S_ + kt + cs], &Vs[buf][db]);
        }
    };

    const int kend = q0 + 128;
    STAGE(0, 0);
    int cur = 0;

    for (int kt = 0; kt < kend; kt += 128) {
        if (kt + 128 < kend) {
            STAGE(cur ^ 1, kt + 128);
            asm volatile("s_waitcnt vmcnt(8)" ::: "memory");  // current tile only
        } else {
            asm volatile("s_waitcnt vmcnt(0)" ::: "memory");
        }
        __builtin_amdgcn_s_barrier();

        {
            const ushort* Kc = &Ks[cur][0];
            const ushort* Vc = &Vs[cur][0];

            // ---- S^T = K @ Q^T over 128 keys: all 4 subs ISSUED up front ----
            f32x16 sacc[4] = {};
            __builtin_amdgcn_s_setprio(1);
            #pragma unroll
            for (int sub = 0; sub < 4; ++sub) {
                const int rK = sub * 32 + lq;
                const int rx = lq & 7;
                #pragma unroll
                for (int dc = 0; dc < 4; ++dc) {
                    const bf16x8 kf = *reinterpret_cast<const bf16x8*>(
                        &Kc[rK * 64 + (((2 * dc + hi) ^ rx) * 8)]);
                    sacc[sub] = __builtin_amdgcn_mfma_f32_32x32x16_bf16(
                        kf, qf[dc], sacc[sub], 0, 0, 0);
                }
            }
            __builtin_amdgcn_s_setprio(0);

            // ---- two sequential 64-key online-softmax updates ----
            #pragma unroll
            for (int hf = 0; hf < 2; ++hf) {
                const int sA = 2 * hf, sB = 2 * hf + 1;

                // causal mask (boundary subs only; full-masked subs -> p=0)
                #pragma unroll
                for (int sub = sA; sub <= sB; ++sub)
                    if (kt + sub * 32 + 31 > qw) {
                        #pragma unroll
                        for (int r = 0; r < 16; ++r) {
                            const int kg = kt + sub * 32 + (r & 3) + 8 * (r >> 2) + 4 * hi;
                            if (kg > qg) sacc[sub][r] = -1.0e30f;
                        }
                    }

                // row max over this half's 64 scores: tree + cross-half swap
                float mx[16];
                #pragma unroll
                for (int r = 0; r < 16; ++r)
                    mx[r] = fmaxf(sacc[sA][r], sacc[sB][r]);
                #pragma unroll
                for (int s2 = 8; s2 > 0; s2 >>= 1)
                    #pragma unroll
                    for (int r = 0; r < s2; ++r) mx[r] = fmaxf(mx[r], mx[r + s2]);
                const float tm = fmaxf(mx[0], __shfl_xor(mx[0], 32));

                // rescale (exact skip when no lane has a new max)
                if (!__all(tm <= mrow)) {
                    const float mnew = fmaxf(mrow, tm);
                    const float corr = hw_exp2(mrow - mnew);
                    lrow *= corr;
                    #pragma unroll
                    for (int r = 0; r < 16; ++r) { oacc[0][r] *= corr; oacc[1][r] *= corr; }
                    mrow = mnew;
                }

                // p = exp2(s - m); tree row-sum for this half
                float sm[16];
                #pragma unroll
                for (int sub = sA; sub <= sB; ++sub)
                    #pragma unroll
                    for (int r = 0; r < 16; ++r)
                        sacc[sub][r] = hw_exp2(sacc[sub][r] - mrow);
                #pragma unroll
                for (int r = 0; r < 16; ++r) sm[r] = sacc[sA][r] + sacc[sB][r];
                #pragma unroll
                for (int s2 = 8; s2 > 0; s2 >>= 1)
                    #pragma unroll
                    for (int r = 0; r < s2; ++r) sm[r] += sm[r + s2];
                lrow += sm[0] + __shfl_xor(sm[0], 32);

                // per sub: pack P and O^T += V^T @ P^T (V frags scoped)
                #pragma unroll
                for (int sub = sA; sub <= sB; ++sub) {
                    u32 wpk[8];
                    #pragma unroll
                    for (int i = 0; i < 8; ++i)
                        wpk[i] = cvtpk_bf16(sacc[sub][2 * i], sacc[sub][2 * i + 1]);
                    u32 a0 = wpk[0], b0 = wpk[2];
                    u32 a1 = wpk[1], b1 = wpk[3];
                    u32 a2 = wpk[4], b2 = wpk[6];
                    u32 a3 = wpk[5], b3 = wpk[7];
                    asm("v_permlane32_swap_b32 %0, %1" : "+v"(a0), "+v"(b0));
                    asm("v_permlane32_swap_b32 %0, %1" : "+v"(a1), "+v"(b1));
                    asm("v_permlane32_swap_b32 %0, %1" : "+v"(a2), "+v"(b2));
                    asm("v_permlane32_swap_b32 %0, %1" : "+v"(a3), "+v"(b3));
                    u32x4 pw0, pw1;
                    pw0[0] = a0; pw0[1] = a1; pw0[2] = b0; pw0[3] = b1;
                    pw1[0] = a2; pw1[1] = a3; pw1[2] = b2; pw1[3] = b3;
                    const bf16x8 pb0 = __builtin_bit_cast(bf16x8, pw0);
                    const bf16x8 pb1 = __builtin_bit_cast(bf16x8, pw1);
                    __builtin_amdgcn_s_setprio(1);
                    #pragma unroll
                    for (int dt = 0; dt < 2; ++dt) {
                        const int rV = dt * 32 + lq;
                        const int jx = lq & 15;
                        const bf16x8 v0 = *reinterpret_cast<const bf16x8*>(
                            &Vc[rV * 128 + (((sub * 4 + 0 * 2 + hi) ^ jx) * 8)]);
                        oacc[dt] = __builtin_amdgcn_mfma_f32_32x32x16_bf16(
                            v0, pb0, oacc[dt], 0, 0, 0);
                        const bf16x8 v1 = *reinterpret_cast<const bf16x8*>(
                            &Vc[rV * 128 + (((sub * 4 + 1 * 2 + hi) ^ jx) * 8)]);
                        oacc[dt] = __builtin_amdgcn_mfma_f32_32x32x16_bf16(
                            v1, pb1, oacc[dt], 0, 0, 0);
                    }
                    __builtin_amdgcn_s_setprio(0);
                }
            }
        }
        __builtin_amdgcn_s_barrier();
        cur ^= 1;
    }

    // ---- epilogue: O^T / l -> AO[q][d] (lane's own q row) ----
    const float inv = 1.f / lrow;
    ushort* aorow = AO + (size_t)(b * S_ + qg) * 1024 + h * 64;
    #pragma unroll
    for (int dt = 0; dt < 2; ++dt)
        #pragma unroll
        for (int g = 0; g < 4; ++g) {
            const int d0 = dt * 32 + g * 8 + hi * 4;
            ushort4v pk;
            #pragma unroll
            for (int j = 0; j < 4; ++j) pk[j] = f2bf(oacc[dt][g * 4 + j] * inv);
            *reinterpret_cast<ushort4v*>(&aorow[d0]) = pk;
        }
}

// ---------------------------------------------------------------------------
extern "C" void kernel_launch(void* const* d_in, const int* in_sizes, int n_in,
                              void* d_out, int out_size, void* d_ws, size_t ws_size,
                              hipStream_t stream)
{
    const float* x  = (const float*)d_in[0];
    const float* Wq = (const float*)d_in[2];
    const float* bq = (const float*)d_in[3];
    const float* Wk = (const float*)d_in[4];
    const float* bk = (const float*)d_in[5];
    const float* Wv = (const float*)d_in[6];
    const float* bv = (const float*)d_in[7];
    const float* Wo = (const float*)d_in[8];
    const float* bo = (const float*)d_in[9];
    float* out = (float*)d_out;

    const size_t tok = (size_t)B_ * S_;            // 4096
    ushort* xb    = (ushort*)d_ws;                 // 4M elems
    ushort* WtQKV = xb + tok * E_;                 // 3M
    ushort* WtO   = WtQKV + (size_t)3072 * 1024;   // 1M
    ushort* Qb    = WtO + (size_t)1024 * 1024;     // 4M
    ushort* Kb    = Qb + tok * E_;                 // 4M
    ushort* Vt    = Kb + tok * E_;                 // 4M
    ushort* AO    = Vt + tok * E_;                 // 4M

    cast_x<<<2048, 256, 0, stream>>>(x, xb);
    castT_w<<<dim3(32, 16, 4), 256, 0, stream>>>(Wq, Wk, Wv, Wo, WtQKV, WtO);

    gemm_qkv<<<dim3(24, 32), 256, 0, stream>>>(xb, WtQKV, bq, bk, bv, Qb, Kb, Vt);

    attn13<<<512, 256, 0, stream>>>(Qb, Kb, Vt, AO);

    gemm_out<<<dim3(8, 32), 256, 0, stream>>>(AO, WtO, bo, out, 1024, 1024);
}

// Round 20
// 105.507 us; speedup vs baseline: 1.1163x; 1.0271x over previous
//
#include <hip/hip_runtime.h>
#include <cmath>

#define B_ 2
#define S_ 2048
#define E_ 1024
#define H_ 16
#define D_ 64

typedef __attribute__((ext_vector_type(8)))  short  bf16x8;
typedef __attribute__((ext_vector_type(4)))  float  f32x4;
typedef __attribute__((ext_vector_type(16))) float  f32x16;
typedef __attribute__((ext_vector_type(8)))  unsigned short ushort8;
typedef __attribute__((ext_vector_type(4)))  unsigned short ushort4v;
typedef __attribute__((ext_vector_type(4)))  unsigned int   u32x4;
typedef unsigned int u32;

__device__ __forceinline__ ushort f2bf(float f) {
    u32 u = __float_as_uint(f);
    u32 r = (u + 0x7fffu + ((u >> 16) & 1u)) >> 16;
    return (ushort)r;
}
__device__ __forceinline__ void gload_lds16(const ushort* gp, ushort* lp) {
    auto g = (const __attribute__((address_space(1))) u32*)gp;
    auto l = (__attribute__((address_space(3))) u32*)lp;
    __builtin_amdgcn_global_load_lds(g, l, 16, 0, 0);
}
__device__ __forceinline__ u32 cvtpk_bf16(float lo, float hi) {
    u32 r;
    asm("v_cvt_pk_bf16_f32 %0, %1, %2" : "=v"(r) : "v"(lo), "v"(hi));
    return r;
}
// raw v_exp_f32 (2^x); input always <= 0 here, hw handles -inf -> 0
__device__ __forceinline__ float hw_exp2(float x) {
    float r;
    asm("v_exp_f32 %0, %1" : "=v"(r) : "v"(x));
    return r;
}
// hardware sin/cos of (2*pi*rev); v_fract first keeps input in-domain
__device__ __forceinline__ void hw_sincos_rev(float rev, float* sn, float* cs) {
    float fr;
    asm("v_fract_f32 %0, %1" : "=v"(fr) : "v"(rev));
    asm("v_sin_f32 %0, %1" : "=v"(*sn) : "v"(fr));
    asm("v_cos_f32 %0, %1" : "=v"(*cs) : "v"(fr));
}

// ---------------------------------------------------------------------------
// fused casts: blocks 0..2047 cast x (f32->bf16, 8 elems/thread);
// blocks 2048..4095 cast+transpose the four weight matrices (64-k tiles,
// packed u32 stores).  One dispatch instead of two: removes a launch-drain
// gap and overlaps the two BW-bound phases.
// ---------------------------------------------------------------------------
__global__ __launch_bounds__(256) void fused_casts(
    const float* __restrict__ x, ushort* __restrict__ xb,
    const float* __restrict__ Wq, const float* __restrict__ Wk,
    const float* __restrict__ Wv, const float* __restrict__ Wo,
    ushort* __restrict__ WtQKV, ushort* __restrict__ WtO)
{
    __shared__ float tile[64][33];

    if (blockIdx.x < 2048) {
        // ---- cast_x ----
        const int idx = blockIdx.x * 256 + threadIdx.x;
        const float4 a = *reinterpret_cast<const float4*>(&x[(size_t)idx * 8]);
        const float4 b = *reinterpret_cast<const float4*>(&x[(size_t)idx * 8 + 4]);
        ushort8 o;
        o[0] = f2bf(a.x); o[1] = f2bf(a.y); o[2] = f2bf(a.z); o[3] = f2bf(a.w);
        o[4] = f2bf(b.x); o[5] = f2bf(b.y); o[6] = f2bf(b.z); o[7] = f2bf(b.w);
        *reinterpret_cast<ushort8*>(&xb[(size_t)idx * 8]) = o;
        return;
    }

    // ---- castT_w ----
    const int lin = blockIdx.x - 2048;         // 0..2047
    const int z   = lin >> 9;                  // weight 0..3
    const int rem = lin & 511;
    const int by  = rem >> 5;                  // k-panel 0..15
    const int bx  = rem & 31;                  // n-panel 0..31

    const float* src; ushort* dst;
    switch (z) {
        case 0:  src = Wq; dst = WtQKV;                 break;
        case 1:  src = Wk; dst = WtQKV + 1024 * 1024;   break;
        case 2:  src = Wv; dst = WtQKV + 2048 * 1024;   break;
        default: src = Wo; dst = WtO;                   break;
    }
    const int k0 = by * 64, n0 = bx * 32;
    const int tn = threadIdx.x & 31, tk = threadIdx.x >> 5;   // 0..31, 0..7
    #pragma unroll
    for (int p = 0; p < 8; ++p)
        tile[p * 8 + tk][tn] = src[(size_t)(k0 + p * 8 + tk) * 1024 + n0 + tn];
    __syncthreads();
    const int kp = (threadIdx.x & 31) * 2, nq = threadIdx.x >> 5;
    #pragma unroll
    for (int q = 0; q < 4; ++q) {
        const int n = q * 8 + nq;
        const u32 v = (u32)f2bf(tile[kp][n]) | ((u32)f2bf(tile[kp + 1][n]) << 16);
        *reinterpret_cast<u32*>(&dst[(size_t)(n0 + n) * 1024 + k0 + kp]) = v;
    }
}

// ---------------------------------------------------------------------------
// QKV GEMM (M=4096, N=3072, K=1024), 128x128 tile, BK=64, T2-swizzled LDS.
// Single-buffered (r17 lesson).  T1 XCD-grouping block swizzle (r18,
// neutral but harmless).  Epilogue fuses bias + RoPE; Q scaled by
// 0.125*log2(e).  Writes Q->Qb, K->Kb (row-major), V->Vt (transposed).
// ---------------------------------------------------------------------------
__global__ __launch_bounds__(256, 3) void gemm_qkv(
    const ushort* __restrict__ A, const ushort* __restrict__ Bt,
    const float* __restrict__ bq, const float* __restrict__ bk,
    const float* __restrict__ bv,
    ushort* __restrict__ Qb, ushort* __restrict__ Kb, ushort* __restrict__ Vt)
{
    __shared__ ushort As[128 * 64];
    __shared__ ushort Bs[128 * 64];
    const int t = threadIdx.x, w = t >> 6, l = t & 63;
    const int lr = l & 15, lg = l >> 4;
    const int wr = w >> 1, wc = w & 1;

    // T1 XCD-grouping swizzle (bijective, 768 % 8 == 0)
    const int lin  = blockIdx.y * 24 + blockIdx.x;   // hw dispatch linear id
    const int xcd  = lin & 7;
    const int slot = lin >> 3;                       // 0..95
    const int row0 = (xcd * 4 + slot / 24) * 128;    // row-panel 0..31
    const int col0 = (slot % 24) * 128;              // col-panel 0..23

    f32x4 acc[4][4] = {};

    for (int k0 = 0; k0 < 1024; k0 += 64) {
        #pragma unroll
        for (int i = 0; i < 4; ++i) {
            const int r  = w * 32 + i * 8 + (l >> 3);
            const int cs = ((l & 7) ^ (r & 7)) * 8;          // src pre-swizzle
            gload_lds16(&A [(size_t)(row0 + r) * 1024 + k0 + cs], &As[(w * 32 + i * 8) * 64]);
            gload_lds16(&Bt[(size_t)(col0 + r) * 1024 + k0 + cs], &Bs[(w * 32 + i * 8) * 64]);
        }
        asm volatile("s_waitcnt vmcnt(0)");
        __syncthreads();

        #pragma unroll
        for (int kk = 0; kk < 2; ++kk) {
            bf16x8 af[4], bfr[4];
            #pragma unroll
            for (int m = 0; m < 4; ++m)
                af[m] = *reinterpret_cast<const bf16x8*>(
                    &As[(wr * 64 + m * 16 + lr) * 64 + (((kk * 4 + lg) ^ (lr & 7)) * 8)]);
            #pragma unroll
            for (int n = 0; n < 4; ++n)
                bfr[n] = *reinterpret_cast<const bf16x8*>(
                    &Bs[(wc * 64 + n * 16 + lr) * 64 + (((kk * 4 + lg) ^ (lr & 7)) * 8)]);
            #pragma unroll
            for (int m = 0; m < 4; ++m)
                #pragma unroll
                for (int n = 0; n < 4; ++n)
                    acc[m][n] = __builtin_amdgcn_mfma_f32_16x16x32_bf16(
                        af[m], bfr[n], acc[m][n], 0, 0, 0);
        }
        __syncthreads();
    }

    const int cbase = col0 + wc * 64;          // wave's 64-col span (one head)
    const int cls   = cbase >> 10;             // 0=Q, 1=K, 2=V
    const int hcol  = cbase & 1023;            // head-aligned col within 1024
    const float* bias = (cls == 0) ? bq : (cls == 1 ? bk : bv);

    if (cls < 2) {
        ushort* dst = (cls == 0) ? Qb : Kb;
        const float qscale = (cls == 0) ? 0.1803368801f : 1.0f;  // 0.125*log2(e)
        #pragma unroll
        for (int m = 0; m < 4; ++m) {
            const int rbase = row0 + wr * 64 + m * 16 + lg * 4;
            #pragma unroll
            for (int n = 0; n < 2; ++n) {
                const int i    = n * 16 + lr;                  // 0..31
                const float b0 = bias[hcol + i];
                const float b1 = bias[hcol + i + 32];
                // invf / (2*pi): angle in revolutions = s * invf_rev
                const float invf_rev =
                    exp2f(-(float)i * 0.415241012f) * 0.15915494309f;
                #pragma unroll
                for (int r = 0; r < 4; ++r) {
                    const int row = rbase + r;
                    const int s   = row & (S_ - 1);
                    float sn, cs_;
                    hw_sincos_rev((float)s * invf_rev, &sn, &cs_);
                    const float v0 = acc[m][n][r]     + b0;
                    const float v1 = acc[m][n + 2][r] + b1;
                    dst[(size_t)row * 1024 + hcol + i]      = f2bf((v0 * cs_ - v1 * sn) * qscale);
                    dst[(size_t)row * 1024 + hcol + i + 32] = f2bf((v1 * cs_ + v0 * sn) * qscale);
                }
            }
        }
    } else {
        const int h = hcol >> 6;
        #pragma unroll
        for (int m = 0; m < 4; ++m) {
            const int rbase = row0 + wr * 64 + m * 16 + lg * 4;
            const int bb = rbase >> 11, s0 = rbase & (S_ - 1);
            #pragma unroll
            for (int n = 0; n < 4; ++n) {
                const int d = n * 16 + lr;
                const float bia = bias[hcol + d];
                ushort4v pk;
                #pragma unroll
                for (int r = 0; r < 4; ++r) pk[r] = f2bf(acc[m][n][r] + bia);
                *reinterpret_cast<ushort4v*>(
                    &Vt[((size_t)(bb * 16 + h) * 64 + d) * S_ + s0]) = pk;
            }
        }
    }
}

// ---------------------------------------------------------------------------
// Output GEMM: C[M,1024] f32 = A @ Wt^T + bias.  Dbuf + counted vmcnt(8) +
// raw s_barrier (verified win r12; 1 block/CU so no TLP to lose).
// ---------------------------------------------------------------------------
__global__ __launch_bounds__(256, 1) void gemm_out(
    const ushort* __restrict__ A, const ushort* __restrict__ Bt,
    const float* __restrict__ bias, float* __restrict__ C, int N, int K)
{
    __shared__ ushort As[2][128 * 64];
    __shared__ ushort Bs[2][128 * 64];
    const int t = threadIdx.x, w = t >> 6, l = t & 63;
    const int lr = l & 15, lg = l >> 4;
    const int wr = w >> 1, wc = w & 1;
    const int row0 = blockIdx.y * 128, col0 = blockIdx.x * 128;

    f32x4 acc[4][4] = {};

    auto STAGE = [&](int buf, int k0) {
        #pragma unroll
        for (int i = 0; i < 4; ++i) {
            const int r  = w * 32 + i * 8 + (l >> 3);
            const int cs = ((l & 7) ^ (r & 7)) * 8;
            gload_lds16(&A [(size_t)(row0 + r) * K + k0 + cs], &As[buf][(w * 32 + i * 8) * 64]);
            gload_lds16(&Bt[(size_t)(col0 + r) * K + k0 + cs], &Bs[buf][(w * 32 + i * 8) * 64]);
        }
    };

    STAGE(0, 0);
    int cur = 0;

    for (int k0 = 0; k0 < K; k0 += 64) {
        if (k0 + 64 < K) {
            STAGE(cur ^ 1, k0 + 64);
            asm volatile("s_waitcnt vmcnt(8)" ::: "memory");
        } else {
            asm volatile("s_waitcnt vmcnt(0)" ::: "memory");
        }
        __builtin_amdgcn_s_barrier();

        #pragma unroll
        for (int kk = 0; kk < 2; ++kk) {
            bf16x8 af[4], bfr[4];
            #pragma unroll
            for (int m = 0; m < 4; ++m)
                af[m] = *reinterpret_cast<const bf16x8*>(
                    &As[cur][(wr * 64 + m * 16 + lr) * 64 + (((kk * 4 + lg) ^ (lr & 7)) * 8)]);
            #pragma unroll
            for (int n = 0; n < 4; ++n)
                bfr[n] = *reinterpret_cast<const bf16x8*>(
                    &Bs[cur][(wc * 64 + n * 16 + lr) * 64 + (((kk * 4 + lg) ^ (lr & 7)) * 8)]);
            #pragma unroll
            for (int m = 0; m < 4; ++m)
                #pragma unroll
                for (int n = 0; n < 4; ++n)
                    acc[m][n] = __builtin_amdgcn_mfma_f32_16x16x32_bf16(
                        af[m], bfr[n], acc[m][n], 0, 0, 0);
        }
        __builtin_amdgcn_s_barrier();
        cur ^= 1;
    }

    #pragma unroll
    for (int m = 0; m < 4; ++m) {
        const int rbase = row0 + wr * 64 + m * 16 + lg * 4;
        #pragma unroll
        for (int n = 0; n < 4; ++n) {
            const int c = col0 + wc * 64 + n * 16 + lr;
            const float bv = bias[c];
            #pragma unroll
            for (int r = 0; r < 4; ++r)
                C[(size_t)(rbase + r) * N + c] = acc[m][n][r] + bv;
        }
    }
}

// ---------------------------------------------------------------------------
// attn13 (kept): KVBLK=128, balanced CU pairs, split online softmax
// (2 sequential 64-key flash updates per tile), in-register machinery.
// ---------------------------------------------------------------------------
__global__ __launch_bounds__(256, 2) void attn13(
    const ushort* __restrict__ Qb, const ushort* __restrict__ Kb,
    const ushort* __restrict__ Vt, ushort* __restrict__ AO)
{
    __shared__ ushort Ks[2][128 * 64];
    __shared__ ushort Vs[2][64 * 128];

    const int t = threadIdx.x, w = t >> 6, l = t & 63;
    const int lq = l & 31, hi = l >> 5;
    const int idx = blockIdx.x;
    const int bh = idx & 31, b = bh >> 4, h = bh & 15;
    const int g8 = idx >> 5;                   // 0..15
    const int qb = (idx < 256) ? (15 - g8) : (g8 - 8);   // balanced CU pairs
    const int q0 = qb * 128, qw = q0 + w * 32;
    const int qg = qw + lq;                    // this lane's q row

    const ushort* Kbh = Kb + (size_t)b * S_ * 1024 + h * 64;
    const ushort* Vbh = Vt + (size_t)bh * 64 * S_;

    // Q fragments (B-operand): qf[dc] = Q[qg][16*dc + 8*hi + j]
    bf16x8 qf[4];
    {
        const ushort* qrow = Qb + (size_t)(b * S_ + qg) * 1024 + h * 64 + 8 * hi;
        #pragma unroll
        for (int dc = 0; dc < 4; ++dc)
            qf[dc] = *reinterpret_cast<const bf16x8*>(qrow + 16 * dc);
    }

    f32x16 oacc[2] = {};                       // O^T: rows=d, col=q(lane)
    float mrow = -3.0e38f, lrow = 0.f;

    auto STAGE = [&](int buf, int kt) {
        // K: 128 keys x 64 d, 16 KB -> 4 instrs.  Linear dest, pre-swizzled src.
        #pragma unroll
        for (int i = 0; i < 4; ++i) {
            const int cid = i * 256 + t;                     // 0..1023
            const int r   = cid >> 3;                        // key 0..127
            const int cs  = ((cid & 7) ^ (r & 7)) * 8;
            const int db  = (i * 256 + w * 64) * 8;          // wave-uniform dest
            gload_lds16(&Kbh[(size_t)(kt + r) * 1024 + cs], &Ks[buf][db]);
        }
        // V: 64 d x 128 keys, 16 KB -> 4 instrs.  16-chunk XOR swizzle.
        #pragma unroll
        for (int i = 0; i < 4; ++i) {
            const int cid = i * 256 + t;
            const int d   = cid >> 4;                        // 0..63
            const int cs  = ((cid & 15) ^ (d & 15)) * 8;
            const int db  = (i * 256 + w * 64) * 8;
            gload_lds16(&Vbh[(size_t)d * S_ + kt + cs], &Vs[buf][db]);
        }
    };

    const int kend = q0 + 128;
    STAGE(0, 0);
    int cur = 0;

    for (int kt = 0; kt < kend; kt += 128) {
        if (kt + 128 < kend) {
            STAGE(cur ^ 1, kt + 128);
            asm volatile("s_waitcnt vmcnt(8)" ::: "memory");  // current tile only
        } else {
            asm volatile("s_waitcnt vmcnt(0)" ::: "memory");
        }
        __builtin_amdgcn_s_barrier();

        {
            const ushort* Kc = &Ks[cur][0];
            const ushort* Vc = &Vs[cur][0];

            // ---- S^T = K @ Q^T over 128 keys: all 4 subs ISSUED up front ----
            f32x16 sacc[4] = {};
            __builtin_amdgcn_s_setprio(1);
            #pragma unroll
            for (int sub = 0; sub < 4; ++sub) {
                const int rK = sub * 32 + lq;
                const int rx = lq & 7;
                #pragma unroll
                for (int dc = 0; dc < 4; ++dc) {
                    const bf16x8 kf = *reinterpret_cast<const bf16x8*>(
                        &Kc[rK * 64 + (((2 * dc + hi) ^ rx) * 8)]);
                    sacc[sub] = __builtin_amdgcn_mfma_f32_32x32x16_bf16(
                        kf, qf[dc], sacc[sub], 0, 0, 0);
                }
            }
            __builtin_amdgcn_s_setprio(0);

            // ---- two sequential 64-key online-softmax updates ----
            #pragma unroll
            for (int hf = 0; hf < 2; ++hf) {
                const int sA = 2 * hf, sB = 2 * hf + 1;

                // causal mask (boundary subs only; full-masked subs -> p=0)
                #pragma unroll
                for (int sub = sA; sub <= sB; ++sub)
                    if (kt + sub * 32 + 31 > qw) {
                        #pragma unroll
                        for (int r = 0; r < 16; ++r) {
                            const int kg = kt + sub * 32 + (r & 3) + 8 * (r >> 2) + 4 * hi;
                            if (kg > qg) sacc[sub][r] = -1.0e30f;
                        }
                    }

                // row max over this half's 64 scores: tree + cross-half swap
                float mx[16];
                #pragma unroll
                for (int r = 0; r < 16; ++r)
                    mx[r] = fmaxf(sacc[sA][r], sacc[sB][r]);
                #pragma unroll
                for (int s2 = 8; s2 > 0; s2 >>= 1)
                    #pragma unroll
                    for (int r = 0; r < s2; ++r) mx[r] = fmaxf(mx[r], mx[r + s2]);
                const float tm = fmaxf(mx[0], __shfl_xor(mx[0], 32));

                // rescale (exact skip when no lane has a new max)
                if (!__all(tm <= mrow)) {
                    const float mnew = fmaxf(mrow, tm);
                    const float corr = hw_exp2(mrow - mnew);
                    lrow *= corr;
                    #pragma unroll
                    for (int r = 0; r < 16; ++r) { oacc[0][r] *= corr; oacc[1][r] *= corr; }
                    mrow = mnew;
                }

                // p = exp2(s - m); tree row-sum for this half
                float sm[16];
                #pragma unroll
                for (int sub = sA; sub <= sB; ++sub)
                    #pragma unroll
                    for (int r = 0; r < 16; ++r)
                        sacc[sub][r] = hw_exp2(sacc[sub][r] - mrow);
                #pragma unroll
                for (int r = 0; r < 16; ++r) sm[r] = sacc[sA][r] + sacc[sB][r];
                #pragma unroll
                for (int s2 = 8; s2 > 0; s2 >>= 1)
                    #pragma unroll
                    for (int r = 0; r < s2; ++r) sm[r] += sm[r + s2];
                lrow += sm[0] + __shfl_xor(sm[0], 32);

                // per sub: pack P and O^T += V^T @ P^T (V frags scoped)
                #pragma unroll
                for (int sub = sA; sub <= sB; ++sub) {
                    u32 wpk[8];
                    #pragma unroll
                    for (int i = 0; i < 8; ++i)
                        wpk[i] = cvtpk_bf16(sacc[sub][2 * i], sacc[sub][2 * i + 1]);
                    u32 a0 = wpk[0], b0 = wpk[2];
                    u32 a1 = wpk[1], b1 = wpk[3];
                    u32 a2 = wpk[4], b2 = wpk[6];
                    u32 a3 = wpk[5], b3 = wpk[7];
                    asm("v_permlane32_swap_b32 %0, %1" : "+v"(a0), "+v"(b0));
                    asm("v_permlane32_swap_b32 %0, %1" : "+v"(a1), "+v"(b1));
                    asm("v_permlane32_swap_b32 %0, %1" : "+v"(a2), "+v"(b2));
                    asm("v_permlane32_swap_b32 %0, %1" : "+v"(a3), "+v"(b3));
                    u32x4 pw0, pw1;
                    pw0[0] = a0; pw0[1] = a1; pw0[2] = b0; pw0[3] = b1;
                    pw1[0] = a2; pw1[1] = a3; pw1[2] = b2; pw1[3] = b3;
                    const bf16x8 pb0 = __builtin_bit_cast(bf16x8, pw0);
                    const bf16x8 pb1 = __builtin_bit_cast(bf16x8, pw1);
                    __builtin_amdgcn_s_setprio(1);
                    #pragma unroll
                    for (int dt = 0; dt < 2; ++dt) {
                        const int rV = dt * 32 + lq;
                        const int jx = lq & 15;
                        const bf16x8 v0 = *reinterpret_cast<const bf16x8*>(
                            &Vc[rV * 128 + (((sub * 4 + 0 * 2 + hi) ^ jx) * 8)]);
                        oacc[dt] = __builtin_amdgcn_mfma_f32_32x32x16_bf16(
                            v0, pb0, oacc[dt], 0, 0, 0);
                        const bf16x8 v1 = *reinterpret_cast<const bf16x8*>(
                            &Vc[rV * 128 + (((sub * 4 + 1 * 2 + hi) ^ jx) * 8)]);
                        oacc[dt] = __builtin_amdgcn_mfma_f32_32x32x16_bf16(
                            v1, pb1, oacc[dt], 0, 0, 0);
                    }
                    __builtin_amdgcn_s_setprio(0);
                }
            }
        }
        __builtin_amdgcn_s_barrier();
        cur ^= 1;
    }

    // ---- epilogue: O^T / l -> AO[q][d] (lane's own q row) ----
    const float inv = 1.f / lrow;
    ushort* aorow = AO + (size_t)(b * S_ + qg) * 1024 + h * 64;
    #pragma unroll
    for (int dt = 0; dt < 2; ++dt)
        #pragma unroll
        for (int g = 0; g < 4; ++g) {
            const int d0 = dt * 32 + g * 8 + hi * 4;
            ushort4v pk;
            #pragma unroll
            for (int j = 0; j < 4; ++j) pk[j] = f2bf(oacc[dt][g * 4 + j] * inv);
            *reinterpret_cast<ushort4v*>(&aorow[d0]) = pk;
        }
}

// ---------------------------------------------------------------------------
extern "C" void kernel_launch(void* const* d_in, const int* in_sizes, int n_in,
                              void* d_out, int out_size, void* d_ws, size_t ws_size,
                              hipStream_t stream)
{
    const float* x  = (const float*)d_in[0];
    const float* Wq = (const float*)d_in[2];
    const float* bq = (const float*)d_in[3];
    const float* Wk = (const float*)d_in[4];
    const float* bk = (const float*)d_in[5];
    const float* Wv = (const float*)d_in[6];
    const float* bv = (const float*)d_in[7];
    const float* Wo = (const float*)d_in[8];
    const float* bo = (const float*)d_in[9];
    float* out = (float*)d_out;

    const size_t tok = (size_t)B_ * S_;            // 4096
    ushort* xb    = (ushort*)d_ws;                 // 4M elems
    ushort* WtQKV = xb + tok * E_;                 // 3M
    ushort* WtO   = WtQKV + (size_t)3072 * 1024;   // 1M
    ushort* Qb    = WtO + (size_t)1024 * 1024;     // 4M
    ushort* Kb    = Qb + tok * E_;                 // 4M
    ushort* Vt    = Kb + tok * E_;                 // 4M
    ushort* AO    = Vt + tok * E_;                 // 4M

    fused_casts<<<4096, 256, 0, stream>>>(x, xb, Wq, Wk, Wv, Wo, WtQKV, WtO);

    gemm_qkv<<<dim3(24, 32), 256, 0, stream>>>(xb, WtQKV, bq, bk, bv, Qb, Kb, Vt);

    attn13<<<512, 256, 0, stream>>>(Qb, Kb, Vt, AO);

    gemm_out<<<dim3(8, 32), 256, 0, stream>>>(AO, WtO, bo, out, 1024, 1024);
}

// Round 21
// 103.120 us; speedup vs baseline: 1.1422x; 1.0232x over previous
//
#include <hip/hip_runtime.h>
#include <cmath>

#define B_ 2
#define S_ 2048
#define E_ 1024
#define H_ 16
#define D_ 64

typedef __attribute__((ext_vector_type(8)))  short  bf16x8;
typedef __attribute__((ext_vector_type(4)))  float  f32x4;
typedef __attribute__((ext_vector_type(16))) float  f32x16;
typedef __attribute__((ext_vector_type(8)))  unsigned short ushort8;
typedef __attribute__((ext_vector_type(4)))  unsigned short ushort4v;
typedef __attribute__((ext_vector_type(4)))  unsigned int   u32x4;
typedef unsigned int u32;

__device__ __forceinline__ ushort f2bf(float f) {
    u32 u = __float_as_uint(f);
    u32 r = (u + 0x7fffu + ((u >> 16) & 1u)) >> 16;
    return (ushort)r;
}
__device__ __forceinline__ float bf2f(ushort u) {
    return __uint_as_float(((u32)u) << 16);
}
__device__ __forceinline__ void gload_lds16(const ushort* gp, ushort* lp) {
    auto g = (const __attribute__((address_space(1))) u32*)gp;
    auto l = (__attribute__((address_space(3))) u32*)lp;
    __builtin_amdgcn_global_load_lds(g, l, 16, 0, 0);
}
__device__ __forceinline__ u32 cvtpk_bf16(float lo, float hi) {
    u32 r;
    asm("v_cvt_pk_bf16_f32 %0, %1, %2" : "=v"(r) : "v"(lo), "v"(hi));
    return r;
}
// raw v_exp_f32 (2^x); input always <= 0 here, hw handles -inf -> 0
__device__ __forceinline__ float hw_exp2(float x) {
    float r;
    asm("v_exp_f32 %0, %1" : "=v"(r) : "v"(x));
    return r;
}
// hardware sin/cos of (2*pi*rev); v_fract first keeps input in-domain
__device__ __forceinline__ void hw_sincos_rev(float rev, float* sn, float* cs) {
    float fr;
    asm("v_fract_f32 %0, %1" : "=v"(fr) : "v"(rev));
    asm("v_sin_f32 %0, %1" : "=v"(*sn) : "v"(fr));
    asm("v_cos_f32 %0, %1" : "=v"(*cs) : "v"(fr));
}

// ---------------------------------------------------------------------------
// fused casts: blocks 0..2047 cast x (f32->bf16); blocks 2048..4095 cast+
// transpose the four weight matrices.
// ---------------------------------------------------------------------------
__global__ __launch_bounds__(256) void fused_casts(
    const float* __restrict__ x, ushort* __restrict__ xb,
    const float* __restrict__ Wq, const float* __restrict__ Wk,
    const float* __restrict__ Wv, const float* __restrict__ Wo,
    ushort* __restrict__ WtQKV, ushort* __restrict__ WtO)
{
    __shared__ float tile[64][33];

    if (blockIdx.x < 2048) {
        const int idx = blockIdx.x * 256 + threadIdx.x;
        const float4 a = *reinterpret_cast<const float4*>(&x[(size_t)idx * 8]);
        const float4 b = *reinterpret_cast<const float4*>(&x[(size_t)idx * 8 + 4]);
        ushort8 o;
        o[0] = f2bf(a.x); o[1] = f2bf(a.y); o[2] = f2bf(a.z); o[3] = f2bf(a.w);
        o[4] = f2bf(b.x); o[5] = f2bf(b.y); o[6] = f2bf(b.z); o[7] = f2bf(b.w);
        *reinterpret_cast<ushort8*>(&xb[(size_t)idx * 8]) = o;
        return;
    }

    const int lin = blockIdx.x - 2048;
    const int z   = lin >> 9;
    const int rem = lin & 511;
    const int by  = rem >> 5;
    const int bx  = rem & 31;

    const float* src; ushort* dst;
    switch (z) {
        case 0:  src = Wq; dst = WtQKV;                 break;
        case 1:  src = Wk; dst = WtQKV + 1024 * 1024;   break;
        case 2:  src = Wv; dst = WtQKV + 2048 * 1024;   break;
        default: src = Wo; dst = WtO;                   break;
    }
    const int k0 = by * 64, n0 = bx * 32;
    const int tn = threadIdx.x & 31, tk = threadIdx.x >> 5;
    #pragma unroll
    for (int p = 0; p < 8; ++p)
        tile[p * 8 + tk][tn] = src[(size_t)(k0 + p * 8 + tk) * 1024 + n0 + tn];
    __syncthreads();
    const int kp = (threadIdx.x & 31) * 2, nq = threadIdx.x >> 5;
    #pragma unroll
    for (int q = 0; q < 4; ++q) {
        const int n = q * 8 + nq;
        const u32 v = (u32)f2bf(tile[kp][n]) | ((u32)f2bf(tile[kp + 1][n]) << 16);
        *reinterpret_cast<u32*>(&dst[(size_t)(n0 + n) * 1024 + k0 + kp]) = v;
    }
}

// ---------------------------------------------------------------------------
// QKV GEMM (M=4096, N=3072, K=1024), 128x128 tile, BK=64, T2-swizzled LDS.
// Single-buffered; T1 XCD-grouping swizzle.  Epilogue fuses bias + RoPE;
// Q scaled by 0.125*log2(e).  Writes Q->Qb, K->Kb, V->Vt (transposed).
// ---------------------------------------------------------------------------
__global__ __launch_bounds__(256, 3) void gemm_qkv(
    const ushort* __restrict__ A, const ushort* __restrict__ Bt,
    const float* __restrict__ bq, const float* __restrict__ bk,
    const float* __restrict__ bv,
    ushort* __restrict__ Qb, ushort* __restrict__ Kb, ushort* __restrict__ Vt)
{
    __shared__ ushort As[128 * 64];
    __shared__ ushort Bs[128 * 64];
    const int t = threadIdx.x, w = t >> 6, l = t & 63;
    const int lr = l & 15, lg = l >> 4;
    const int wr = w >> 1, wc = w & 1;

    const int lin  = blockIdx.y * 24 + blockIdx.x;
    const int xcd  = lin & 7;
    const int slot = lin >> 3;
    const int row0 = (xcd * 4 + slot / 24) * 128;
    const int col0 = (slot % 24) * 128;

    f32x4 acc[4][4] = {};

    for (int k0 = 0; k0 < 1024; k0 += 64) {
        #pragma unroll
        for (int i = 0; i < 4; ++i) {
            const int r  = w * 32 + i * 8 + (l >> 3);
            const int cs = ((l & 7) ^ (r & 7)) * 8;
            gload_lds16(&A [(size_t)(row0 + r) * 1024 + k0 + cs], &As[(w * 32 + i * 8) * 64]);
            gload_lds16(&Bt[(size_t)(col0 + r) * 1024 + k0 + cs], &Bs[(w * 32 + i * 8) * 64]);
        }
        asm volatile("s_waitcnt vmcnt(0)");
        __syncthreads();

        #pragma unroll
        for (int kk = 0; kk < 2; ++kk) {
            bf16x8 af[4], bfr[4];
            #pragma unroll
            for (int m = 0; m < 4; ++m)
                af[m] = *reinterpret_cast<const bf16x8*>(
                    &As[(wr * 64 + m * 16 + lr) * 64 + (((kk * 4 + lg) ^ (lr & 7)) * 8)]);
            #pragma unroll
            for (int n = 0; n < 4; ++n)
                bfr[n] = *reinterpret_cast<const bf16x8*>(
                    &Bs[(wc * 64 + n * 16 + lr) * 64 + (((kk * 4 + lg) ^ (lr & 7)) * 8)]);
            #pragma unroll
            for (int m = 0; m < 4; ++m)
                #pragma unroll
                for (int n = 0; n < 4; ++n)
                    acc[m][n] = __builtin_amdgcn_mfma_f32_16x16x32_bf16(
                        af[m], bfr[n], acc[m][n], 0, 0, 0);
        }
        __syncthreads();
    }

    const int cbase = col0 + wc * 64;
    const int cls   = cbase >> 10;
    const int hcol  = cbase & 1023;
    const float* bias = (cls == 0) ? bq : (cls == 1 ? bk : bv);

    if (cls < 2) {
        ushort* dst = (cls == 0) ? Qb : Kb;
        const float qscale = (cls == 0) ? 0.1803368801f : 1.0f;
        #pragma unroll
        for (int m = 0; m < 4; ++m) {
            const int rbase = row0 + wr * 64 + m * 16 + lg * 4;
            #pragma unroll
            for (int n = 0; n < 2; ++n) {
                const int i    = n * 16 + lr;
                const float b0 = bias[hcol + i];
                const float b1 = bias[hcol + i + 32];
                const float invf_rev =
                    exp2f(-(float)i * 0.415241012f) * 0.15915494309f;
                #pragma unroll
                for (int r = 0; r < 4; ++r) {
                    const int row = rbase + r;
                    const int s   = row & (S_ - 1);
                    float sn, cs_;
                    hw_sincos_rev((float)s * invf_rev, &sn, &cs_);
                    const float v0 = acc[m][n][r]     + b0;
                    const float v1 = acc[m][n + 2][r] + b1;
                    dst[(size_t)row * 1024 + hcol + i]      = f2bf((v0 * cs_ - v1 * sn) * qscale);
                    dst[(size_t)row * 1024 + hcol + i + 32] = f2bf((v1 * cs_ + v0 * sn) * qscale);
                }
            }
        }
    } else {
        const int h = hcol >> 6;
        #pragma unroll
        for (int m = 0; m < 4; ++m) {
            const int rbase = row0 + wr * 64 + m * 16 + lg * 4;
            const int bb = rbase >> 11, s0 = rbase & (S_ - 1);
            #pragma unroll
            for (int n = 0; n < 4; ++n) {
                const int d = n * 16 + lr;
                const float bia = bias[hcol + d];
                ushort4v pk;
                #pragma unroll
                for (int r = 0; r < 4; ++r) pk[r] = f2bf(acc[m][n][r] + bia);
                *reinterpret_cast<ushort4v*>(
                    &Vt[((size_t)(bb * 16 + h) * 64 + d) * S_ + s0]) = pk;
            }
        }
    }
}

// ---------------------------------------------------------------------------
// Output GEMM: C[M,1024] f32 = A @ Wt^T + bias.  Dbuf + counted vmcnt(8) +
// raw s_barrier (verified win r12; 1 block/CU so no TLP to lose).
// ---------------------------------------------------------------------------
__global__ __launch_bounds__(256, 1) void gemm_out(
    const ushort* __restrict__ A, const ushort* __restrict__ Bt,
    const float* __restrict__ bias, float* __restrict__ C, int N, int K)
{
    __shared__ ushort As[2][128 * 64];
    __shared__ ushort Bs[2][128 * 64];
    const int t = threadIdx.x, w = t >> 6, l = t & 63;
    const int lr = l & 15, lg = l >> 4;
    const int wr = w >> 1, wc = w & 1;
    const int row0 = blockIdx.y * 128, col0 = blockIdx.x * 128;

    f32x4 acc[4][4] = {};

    auto STAGE = [&](int buf, int k0) {
        #pragma unroll
        for (int i = 0; i < 4; ++i) {
            const int r  = w * 32 + i * 8 + (l >> 3);
            const int cs = ((l & 7) ^ (r & 7)) * 8;
            gload_lds16(&A [(size_t)(row0 + r) * K + k0 + cs], &As[buf][(w * 32 + i * 8) * 64]);
            gload_lds16(&Bt[(size_t)(col0 + r) * K + k0 + cs], &Bs[buf][(w * 32 + i * 8) * 64]);
        }
    };

    STAGE(0, 0);
    int cur = 0;

    for (int k0 = 0; k0 < K; k0 += 64) {
        if (k0 + 64 < K) {
            STAGE(cur ^ 1, k0 + 64);
            asm volatile("s_waitcnt vmcnt(8)" ::: "memory");
        } else {
            asm volatile("s_waitcnt vmcnt(0)" ::: "memory");
        }
        __builtin_amdgcn_s_barrier();

        #pragma unroll
        for (int kk = 0; kk < 2; ++kk) {
            bf16x8 af[4], bfr[4];
            #pragma unroll
            for (int m = 0; m < 4; ++m)
                af[m] = *reinterpret_cast<const bf16x8*>(
                    &As[cur][(wr * 64 + m * 16 + lr) * 64 + (((kk * 4 + lg) ^ (lr & 7)) * 8)]);
            #pragma unroll
            for (int n = 0; n < 4; ++n)
                bfr[n] = *reinterpret_cast<const bf16x8*>(
                    &Bs[cur][(wc * 64 + n * 16 + lr) * 64 + (((kk * 4 + lg) ^ (lr & 7)) * 8)]);
            #pragma unroll
            for (int m = 0; m < 4; ++m)
                #pragma unroll
                for (int n = 0; n < 4; ++n)
                    acc[m][n] = __builtin_amdgcn_mfma_f32_16x16x32_bf16(
                        af[m], bfr[n], acc[m][n], 0, 0, 0);
        }
        __builtin_amdgcn_s_barrier();
        cur ^= 1;
    }

    #pragma unroll
    for (int m = 0; m < 4; ++m) {
        const int rbase = row0 + wr * 64 + m * 16 + lg * 4;
        #pragma unroll
        for (int n = 0; n < 4; ++n) {
            const int c = col0 + wc * 64 + n * 16 + lr;
            const float bv = bias[c];
            #pragma unroll
            for (int r = 0; r < 4; ++r)
                C[(size_t)(rbase + r) * N + c] = acc[m][n][r] + bv;
        }
    }
}

// ---------------------------------------------------------------------------
// attn14: partial split-K to raise TLP 2 -> 3 waves/SIMD.
// Grid 768 (3 blocks/CU, single-buffered 32 KB LDS).  Block groups:
//   g0 (idx<256):    qb = qq (0..7), all tiles          -> writes AO direct
//   g1 (256..511):   qb = 15-qq, even tiles (s=0)       -> writes partials
//   g2 (512..767):   qb = 15-qq, odd  tiles (s=1)       -> writes partials
// CU triple (idx, idx+256, idx+512) processes exactly (qq+1)+(16-qq) = 17
// tiles.  Online softmax is exact over any tile subset; merge_split does
// the exact flash-merge of the two partials.  Tile-compute body = attn13's.
// ---------------------------------------------------------------------------
__global__ __launch_bounds__(256, 3) void attn14(
    const ushort* __restrict__ Qb, const ushort* __restrict__ Kb,
    const ushort* __restrict__ Vt, ushort* __restrict__ AO,
    ushort* __restrict__ PartO, float2* __restrict__ PartML)
{
    __shared__ ushort Ks[128 * 64];
    __shared__ ushort Vs[64 * 128];

    const int t = threadIdx.x, w = t >> 6, l = t & 63;
    const int lq = l & 31, hi = l >> 5;
    const int idx = blockIdx.x;
    const int g = idx >> 8;                    // 0 unsplit, 1 s=0, 2 s=1
    const int j = idx & 255;
    const int bh = j & 31, b = bh >> 4, h = bh & 15;
    const int qq = j >> 5;                     // 0..7
    const int qb     = (g == 0) ? qq : (15 - qq);
    const int tstart = (g == 2) ? 1 : 0;
    const int tstep  = (g == 0) ? 1 : 2;
    const int q0 = qb * 128, qw = q0 + w * 32;
    const int qg = qw + lq;                    // this lane's q row
    const int nt = qb + 1;                     // 128-key tiles in range

    const ushort* Kbh = Kb + (size_t)b * S_ * 1024 + h * 64;
    const ushort* Vbh = Vt + (size_t)bh * 64 * S_;

    // Q fragments (B-operand): qf[dc] = Q[qg][16*dc + 8*hi + j]
    bf16x8 qf[4];
    {
        const ushort* qrow = Qb + (size_t)(b * S_ + qg) * 1024 + h * 64 + 8 * hi;
        #pragma unroll
        for (int dc = 0; dc < 4; ++dc)
            qf[dc] = *reinterpret_cast<const bf16x8*>(qrow + 16 * dc);
    }

    f32x16 oacc[2] = {};                       // O^T: rows=d, col=q(lane)
    float mrow = -3.0e38f, lrow = 0.f;

    auto STAGE = [&](int kt) {
        #pragma unroll
        for (int i = 0; i < 4; ++i) {
            const int cid = i * 256 + t;
            const int r   = cid >> 3;
            const int cs  = ((cid & 7) ^ (r & 7)) * 8;
            const int db  = (i * 256 + w * 64) * 8;
            gload_lds16(&Kbh[(size_t)(kt + r) * 1024 + cs], &Ks[db]);
        }
        #pragma unroll
        for (int i = 0; i < 4; ++i) {
            const int cid = i * 256 + t;
            const int d   = cid >> 4;
            const int cs  = ((cid & 15) ^ (d & 15)) * 8;
            const int db  = (i * 256 + w * 64) * 8;
            gload_lds16(&Vbh[(size_t)d * S_ + kt + cs], &Vs[db]);
        }
    };

    for (int tt = tstart; tt < nt; tt += tstep) {
        const int kt = tt * 128;
        STAGE(kt);
        asm volatile("s_waitcnt vmcnt(0)" ::: "memory");
        __builtin_amdgcn_s_barrier();

        {
            const ushort* Kc = &Ks[0];
            const ushort* Vc = &Vs[0];

            // ---- S^T = K @ Q^T over 128 keys: all 4 subs issued up front ----
            f32x16 sacc[4] = {};
            __builtin_amdgcn_s_setprio(1);
            #pragma unroll
            for (int sub = 0; sub < 4; ++sub) {
                const int rK = sub * 32 + lq;
                const int rx = lq & 7;
                #pragma unroll
                for (int dc = 0; dc < 4; ++dc) {
                    const bf16x8 kf = *reinterpret_cast<const bf16x8*>(
                        &Kc[rK * 64 + (((2 * dc + hi) ^ rx) * 8)]);
                    sacc[sub] = __builtin_amdgcn_mfma_f32_32x32x16_bf16(
                        kf, qf[dc], sacc[sub], 0, 0, 0);
                }
            }
            __builtin_amdgcn_s_setprio(0);

            // ---- two sequential 64-key online-softmax updates ----
            #pragma unroll
            for (int hf = 0; hf < 2; ++hf) {
                const int sA = 2 * hf, sB = 2 * hf + 1;

                #pragma unroll
                for (int sub = sA; sub <= sB; ++sub)
                    if (kt + sub * 32 + 31 > qw) {
                        #pragma unroll
                        for (int r = 0; r < 16; ++r) {
                            const int kg = kt + sub * 32 + (r & 3) + 8 * (r >> 2) + 4 * hi;
                            if (kg > qg) sacc[sub][r] = -1.0e30f;
                        }
                    }

                float mx[16];
                #pragma unroll
                for (int r = 0; r < 16; ++r)
                    mx[r] = fmaxf(sacc[sA][r], sacc[sB][r]);
                #pragma unroll
                for (int s2 = 8; s2 > 0; s2 >>= 1)
                    #pragma unroll
                    for (int r = 0; r < s2; ++r) mx[r] = fmaxf(mx[r], mx[r + s2]);
                const float tm = fmaxf(mx[0], __shfl_xor(mx[0], 32));

                if (!__all(tm <= mrow)) {
                    const float mnew = fmaxf(mrow, tm);
                    const float corr = hw_exp2(mrow - mnew);
                    lrow *= corr;
                    #pragma unroll
                    for (int r = 0; r < 16; ++r) { oacc[0][r] *= corr; oacc[1][r] *= corr; }
                    mrow = mnew;
                }

                float sm[16];
                #pragma unroll
                for (int sub = sA; sub <= sB; ++sub)
                    #pragma unroll
                    for (int r = 0; r < 16; ++r)
                        sacc[sub][r] = hw_exp2(sacc[sub][r] - mrow);
                #pragma unroll
                for (int r = 0; r < 16; ++r) sm[r] = sacc[sA][r] + sacc[sB][r];
                #pragma unroll
                for (int s2 = 8; s2 > 0; s2 >>= 1)
                    #pragma unroll
                    for (int r = 0; r < s2; ++r) sm[r] += sm[r + s2];
                lrow += sm[0] + __shfl_xor(sm[0], 32);

                #pragma unroll
                for (int sub = sA; sub <= sB; ++sub) {
                    u32 wpk[8];
                    #pragma unroll
                    for (int i = 0; i < 8; ++i)
                        wpk[i] = cvtpk_bf16(sacc[sub][2 * i], sacc[sub][2 * i + 1]);
                    u32 a0 = wpk[0], b0 = wpk[2];
                    u32 a1 = wpk[1], b1 = wpk[3];
                    u32 a2 = wpk[4], b2 = wpk[6];
                    u32 a3 = wpk[5], b3 = wpk[7];
                    asm("v_permlane32_swap_b32 %0, %1" : "+v"(a0), "+v"(b0));
                    asm("v_permlane32_swap_b32 %0, %1" : "+v"(a1), "+v"(b1));
                    asm("v_permlane32_swap_b32 %0, %1" : "+v"(a2), "+v"(b2));
                    asm("v_permlane32_swap_b32 %0, %1" : "+v"(a3), "+v"(b3));
                    u32x4 pw0, pw1;
                    pw0[0] = a0; pw0[1] = a1; pw0[2] = b0; pw0[3] = b1;
                    pw1[0] = a2; pw1[1] = a3; pw1[2] = b2; pw1[3] = b3;
                    const bf16x8 pb0 = __builtin_bit_cast(bf16x8, pw0);
                    const bf16x8 pb1 = __builtin_bit_cast(bf16x8, pw1);
                    __builtin_amdgcn_s_setprio(1);
                    #pragma unroll
                    for (int dt = 0; dt < 2; ++dt) {
                        const int rV = dt * 32 + lq;
                        const int jx = lq & 15;
                        const bf16x8 v0 = *reinterpret_cast<const bf16x8*>(
                            &Vc[rV * 128 + (((sub * 4 + 0 * 2 + hi) ^ jx) * 8)]);
                        oacc[dt] = __builtin_amdgcn_mfma_f32_32x32x16_bf16(
                            v0, pb0, oacc[dt], 0, 0, 0);
                        const bf16x8 v1 = *reinterpret_cast<const bf16x8*>(
                            &Vc[rV * 128 + (((sub * 4 + 1 * 2 + hi) ^ jx) * 8)]);
                        oacc[dt] = __builtin_amdgcn_mfma_f32_32x32x16_bf16(
                            v1, pb1, oacc[dt], 0, 0, 0);
                    }
                    __builtin_amdgcn_s_setprio(0);
                }
            }
        }
        __builtin_amdgcn_s_barrier();          // reads done before next STAGE
    }

    if (g == 0) {
        // ---- unsplit: normalized write to AO ----
        const float inv = 1.f / lrow;
        ushort* aorow = AO + (size_t)(b * S_ + qg) * 1024 + h * 64;
        #pragma unroll
        for (int dt = 0; dt < 2; ++dt)
            #pragma unroll
            for (int gg = 0; gg < 4; ++gg) {
                const int d0 = dt * 32 + gg * 8 + hi * 4;
                ushort4v pk;
                #pragma unroll
                for (int jj = 0; jj < 4; ++jj) pk[jj] = f2bf(oacc[dt][gg * 4 + jj] * inv);
                *reinterpret_cast<ushort4v*>(&aorow[d0]) = pk;
            }
    } else {
        // ---- split: unnormalized partial (m, l, O) ----
        const int s    = g - 1;
        const int prow = (bh << 10) + (qg - 1024);           // qg in [1024,2048)
        PartML[(size_t)s * 32768 + prow] = make_float2(mrow, lrow);
        ushort* po = PartO + ((size_t)s * 32768 + prow) * 64;
        #pragma unroll
        for (int dt = 0; dt < 2; ++dt)
            #pragma unroll
            for (int gg = 0; gg < 4; ++gg) {
                const int d0 = dt * 32 + gg * 8 + hi * 4;
                ushort4v pk;
                #pragma unroll
                for (int jj = 0; jj < 4; ++jj) pk[jj] = f2bf(oacc[dt][gg * 4 + jj]);
                *reinterpret_cast<ushort4v*>(&po[d0]) = pk;
            }
    }
}

// ---------------------------------------------------------------------------
// merge_split: exact flash-merge of the two split-K partials for q rows
// 1024..2047 of every (b,h).  One thread per 4 d elements.
// ---------------------------------------------------------------------------
__global__ __launch_bounds__(256) void merge_split(
    const ushort* __restrict__ PartO, const float2* __restrict__ PartML,
    ushort* __restrict__ AO)
{
    const int tid  = blockIdx.x * 256 + threadIdx.x;   // 0 .. 32768*16-1
    const int prow = tid >> 4;
    const int dq   = (tid & 15) * 4;

    const float2 ml0 = PartML[prow];
    const float2 ml1 = PartML[32768 + prow];
    const float M  = fmaxf(ml0.x, ml1.x);
    const float w0 = hw_exp2(ml0.x - M);
    const float w1 = hw_exp2(ml1.x - M);
    const float inv = 1.f / (ml0.y * w0 + ml1.y * w1);

    const ushort4v o0 = *reinterpret_cast<const ushort4v*>(&PartO[(size_t)prow * 64 + dq]);
    const ushort4v o1 = *reinterpret_cast<const ushort4v*>(&PartO[(size_t)(32768 + prow) * 64 + dq]);

    const int bh = prow >> 10, qg = (prow & 1023) + 1024;
    const int b = bh >> 4, h = bh & 15;
    ushort4v outv;
    #pragma unroll
    for (int jj = 0; jj < 4; ++jj)
        outv[jj] = f2bf((bf2f(o0[jj]) * w0 + bf2f(o1[jj]) * w1) * inv);
    *reinterpret_cast<ushort4v*>(
        &AO[(size_t)(b * S_ + qg) * 1024 + h * 64 + dq]) = outv;
}

// ---------------------------------------------------------------------------
extern "C" void kernel_launch(void* const* d_in, const int* in_sizes, int n_in,
                              void* d_out, int out_size, void* d_ws, size_t ws_size,
                              hipStream_t stream)
{
    const float* x  = (const float*)d_in[0];
    const float* Wq = (const float*)d_in[2];
    const float* bq = (const float*)d_in[3];
    const float* Wk = (const float*)d_in[4];
    const float* bk = (const float*)d_in[5];
    const float* Wv = (const float*)d_in[6];
    const float* bv = (const float*)d_in[7];
    const float* Wo = (const float*)d_in[8];
    const float* bo = (const float*)d_in[9];
    float* out = (float*)d_out;

    const size_t tok = (size_t)B_ * S_;            // 4096
    ushort* xb    = (ushort*)d_ws;                 // 4M elems (8 MB)
    ushort* WtQKV = xb + tok * E_;                 // 3M (6 MB)
    ushort* WtO   = WtQKV + (size_t)3072 * 1024;   // 1M (2 MB)
    ushort* Qb    = WtO + (size_t)1024 * 1024;     // 4M
    ushort* Kb    = Qb + tok * E_;                 // 4M
    ushort* Vt    = Kb + tok * E_;                 // 4M
    ushort* AO    = Vt + tok * E_;                 // 4M
    // split-K partials reuse regions dead after gemm_qkv:
    ushort* PartO  = xb;                           // 2*32768*64 ushorts = 8 MB
    float2* PartML = (float2*)WtQKV;               // 2*32768 float2 = 512 KB

    fused_casts<<<4096, 256, 0, stream>>>(x, xb, Wq, Wk, Wv, Wo, WtQKV, WtO);

    gemm_qkv<<<dim3(24, 32), 256, 0, stream>>>(xb, WtQKV, bq, bk, bv, Qb, Kb, Vt);

    attn14<<<768, 256, 0, stream>>>(Qb, Kb, Vt, AO, PartO, PartML);

    merge_split<<<2048, 256, 0, stream>>>(PartO, PartML, AO);

    gemm_out<<<dim3(8, 32), 256, 0, stream>>>(AO, WtO, bo, out, 1024, 1024);
}